// Round 3
// baseline (1956.065 us; speedup 1.0000x reference)
//
#include <hip/hip_runtime.h>

// ---------------------------------------------------------------------------
// DPM_Block — Round 3: f32 output (proven by 4.51-error signature), f32 input
// path via runtime dtype detector. Structure unchanged from Round 2.
// Shapes: B=128, S=49, C=512, L=1000.
// ws layout (floats): m1[0..128) rs1[128..) m2[256..) rs2[384..)
//   invFt[512..1512) invPr[1536..2536) iflag@3072 | H1@4096 (B*C*S f32)
//   Fvp (B*C) Fvn (B*C) | Fsp bf16 (B*S*C)  — total ~19.8 MB.
// ---------------------------------------------------------------------------

#define Bn 128
#define Sn 49
#define Cn 512
#define Ln 1000
#define BL (Bn*Ln)

typedef unsigned short u16;
typedef unsigned int u32;

__device__ __forceinline__ float bf2f(u16 u){ return __uint_as_float(((u32)u) << 16); }
__device__ __forceinline__ float bflo(u32 u){ return __uint_as_float(u << 16); }
__device__ __forceinline__ float bfhi(u32 u){ return __uint_as_float(u & 0xffff0000u); }
__device__ __forceinline__ u16 f2bf(float f){
  u32 x = __float_as_uint(f);
  u32 r = x + 0x7fffu + ((x >> 16) & 1u);   // round-to-nearest-even
  return (u16)(r >> 16);
}

// generic element load: BF=1 -> bf16, BF=0 -> f32
template<int BF>
__device__ __forceinline__ float ldin(const void* p, int i){
  if (BF) return bf2f(((const u16*)p)[i]);
  return ((const float*)p)[i];
}

// 8 contiguous elements starting at `base` (base % 8 == 0)
template<int BF>
__device__ __forceinline__ void ld8(const void* p, int base, float* w){
  if (BF){
    uint4 u = *(const uint4*)((const u16*)p + base);
    w[0]=bflo(u.x); w[1]=bfhi(u.x); w[2]=bflo(u.y); w[3]=bfhi(u.y);
    w[4]=bflo(u.z); w[5]=bfhi(u.z); w[6]=bflo(u.w); w[7]=bfhi(u.w);
  } else {
    float4 a = *(const float4*)((const float*)p + base);
    float4 b = *(const float4*)((const float*)p + base + 4);
    w[0]=a.x; w[1]=a.y; w[2]=a.z; w[3]=a.w;
    w[4]=b.x; w[5]=b.y; w[6]=b.z; w[7]=b.w;
  }
}

// scalar gamma (expected ~0.99): plausibility-pick so a wrong dtype guess
// can't poison the epilogue.
__device__ __forceinline__ float ld_gamma(const void* p, int BF){
  float fb = bf2f(((const u16*)p)[0]);
  float ff = ((const float*)p)[0];
  bool pb = (fb > 0.05f && fb < 1.5f);
  bool pf = (ff > 0.05f && ff < 1.5f);
  if (pb && !pf) return fb;
  if (pf && !pb) return ff;
  return BF ? fb : ff;
}

// -------------------- dtype detector --------------------
// Sample low-half u16 of the first 256 u32 words of Fs. bf16 N(0,1) data has
// exponent field in [0x70,0x8F] w.p. ~1; f32 data's low halves are mantissa
// bits (~12.5% in range).
__global__ void k_detect(const void* Fs, int* flag){
  int lane = threadIdx.x;
  int v = 0;
  for (int i = lane; i < 256; i += 64){
    u16 lo = ((const u16*)Fs)[2*i];
    int e = (lo >> 7) & 0xff;
    v += (e >= 0x70 && e <= 0x8f);
  }
  #pragma unroll
  for (int off = 32; off; off >>= 1) v += __shfl_xor(v, off);
  if (lane == 0) *flag = (v >= 200) ? 1 : 0;
}

// 256-thread block reduction of two values. scratch = 8 floats.
__device__ __forceinline__ float2 block_red2(float a, float b, float* scratch){
  __syncthreads();
  #pragma unroll
  for (int off = 32; off; off >>= 1){ a += __shfl_xor(a, off); b += __shfl_xor(b, off); }
  int lane = threadIdx.x & 63, wid = threadIdx.x >> 6;
  if (lane == 0){ scratch[wid] = a; scratch[wid + 4] = b; }
  __syncthreads();
  return make_float2(scratch[0] + scratch[1] + scratch[2] + scratch[3],
                     scratch[4] + scratch[5] + scratch[6] + scratch[7]);
}

// -------------------- groupnorm stats --------------------
template<int BF>
__device__ void gn1_body(const void* Fs, float* m1, float* rs1, float* red){
  int b = blockIdx.x, tid = threadIdx.x;
  float s = 0.f, ss = 0.f;
  for (int i = tid; i < Sn*Cn/8; i += 256){
    float w[8]; ld8<BF>(Fs, b*Sn*Cn + i*8, w);
    #pragma unroll
    for (int j = 0; j < 8; ++j){ s += w[j]; ss += w[j]*w[j]; }
  }
  float2 r = block_red2(s, ss, red);
  if (tid == 0){
    float m = r.x * (1.f/(Sn*Cn));
    float v = r.y * (1.f/(Sn*Cn)) - m*m;
    m1[b] = m; rs1[b] = rsqrtf(v + 1e-5f);
  }
}

__global__ __launch_bounds__(256) void k_gn1_stats(const int* fl, const void* Fs,
                                                   float* m1, float* rs1){
  __shared__ float red[8];
  if (*fl) gn1_body<1>(Fs, m1, rs1, red); else gn1_body<0>(Fs, m1, rs1, red);
}

__global__ __launch_bounds__(256) void k_gn2_stats(const float* __restrict__ H1,
                                                   float* __restrict__ m2, float* __restrict__ rs2){
  __shared__ float red[8];
  int b = blockIdx.x, tid = threadIdx.x;
  const float4* p = (const float4*)(H1 + (size_t)b*Sn*Cn);
  float s = 0.f, ss = 0.f;
  for (int i = tid; i < Sn*Cn/4; i += 256){
    float4 v = p[i];
    s += (v.x + v.y) + (v.z + v.w);
    ss += v.x*v.x + v.y*v.y + v.z*v.z + v.w*v.w;
  }
  float2 r = block_red2(s, ss, red);
  if (tid == 0){
    float m = r.x * (1.f/(Sn*Cn));
    float v = r.y * (1.f/(Sn*Cn)) - m*m;
    m2[b] = m; rs2[b] = rsqrtf(v + 1e-5f);
  }
}

// -------------------- conv1: GN1 -> W1 -> +bias -> relu --------------------
#define XP 52   // xt pitch (floats)

template<int BF>
__device__ void conv1_body(const void* Fs, const void* g1, const void* bb1,
    const void* W1, const void* bias1,
    const float* m1, const float* rs1, float* H1, float* xt){
  int b = blockIdx.x >> 1, half = blockIdx.x & 1;
  int tid = threadIdx.x;
  float mean = m1[b], rs = rs1[b];
  for (int i = tid; i < Sn*Cn; i += 256){
    int s = i >> 9, c = i & 511;
    float x = ldin<BF>(Fs, b*Sn*Cn + i);
    xt[c*XP + s] = (x - mean) * rs * ldin<BF>(g1, c) + ldin<BF>(bb1, c);
  }
  __syncthreads();
  int o = half*256 + tid;
  float acc[Sn];
  #pragma unroll
  for (int s = 0; s < Sn; ++s) acc[s] = 0.f;
  for (int k = 0; k < Cn/8; ++k){
    float wv[8]; ld8<BF>(W1, o*Cn + k*8, wv);
    #pragma unroll
    for (int j = 0; j < 8; ++j){
      const float* xr = &xt[(k*8 + j)*XP];
      float w = wv[j];
      #pragma unroll
      for (int s4 = 0; s4 < 48; s4 += 4){
        float4 v = *(const float4*)(xr + s4);
        acc[s4+0] = fmaf(w, v.x, acc[s4+0]);
        acc[s4+1] = fmaf(w, v.y, acc[s4+1]);
        acc[s4+2] = fmaf(w, v.z, acc[s4+2]);
        acc[s4+3] = fmaf(w, v.w, acc[s4+3]);
      }
      acc[48] = fmaf(w, xr[48], acc[48]);
    }
  }
  float bias = ldin<BF>(bias1, o);
  float* dst = H1 + ((size_t)b*Cn + o)*Sn;
  #pragma unroll
  for (int s = 0; s < Sn; ++s) dst[s] = fmaxf(acc[s] + bias, 0.f);
}

__global__ __launch_bounds__(256) void k_conv1(const int* fl, const void* Fs,
    const void* g1, const void* bb1, const void* W1, const void* bias1,
    const float* m1, const float* rs1, float* H1){
  __shared__ float xt[Cn*XP];
  if (*fl) conv1_body<1>(Fs, g1, bb1, W1, bias1, m1, rs1, H1, xt);
  else     conv1_body<0>(Fs, g1, bb1, W1, bias1, m1, rs1, H1, xt);
}

// -------------------- conv2: GN2 -> W2 -> +bias -> Fs_p bf16 ----------------
template<int BF>
__device__ void conv2_body(const float* H1, const void* g2, const void* bb2,
    const void* W2, const void* bias2,
    const float* m2, const float* rs2, u16* Fsp, float* xt){
  int b = blockIdx.x >> 1, half = blockIdx.x & 1;
  int tid = threadIdx.x;
  float mean = m2[b], rs = rs2[b];
  const float* src = H1 + (size_t)b*Cn*Sn;
  for (int i = tid; i < Sn*Cn; i += 256){
    int c = i / Sn, s = i - c*Sn;
    xt[c*XP + s] = (src[i] - mean) * rs * ldin<BF>(g2, c) + ldin<BF>(bb2, c);
  }
  __syncthreads();
  int o = half*256 + tid;
  float acc[Sn];
  #pragma unroll
  for (int s = 0; s < Sn; ++s) acc[s] = 0.f;
  for (int k = 0; k < Cn/8; ++k){
    float wv[8]; ld8<BF>(W2, o*Cn + k*8, wv);
    #pragma unroll
    for (int j = 0; j < 8; ++j){
      const float* xr = &xt[(k*8 + j)*XP];
      float w = wv[j];
      #pragma unroll
      for (int s4 = 0; s4 < 48; s4 += 4){
        float4 v = *(const float4*)(xr + s4);
        acc[s4+0] = fmaf(w, v.x, acc[s4+0]);
        acc[s4+1] = fmaf(w, v.y, acc[s4+1]);
        acc[s4+2] = fmaf(w, v.z, acc[s4+2]);
        acc[s4+3] = fmaf(w, v.w, acc[s4+3]);
      }
      acc[48] = fmaf(w, xr[48], acc[48]);
    }
  }
  float bias = ldin<BF>(bias2, o);
  u16* dst = Fsp + (size_t)b*Sn*Cn + o;
  #pragma unroll
  for (int s = 0; s < Sn; ++s) dst[s*Cn] = f2bf(acc[s] + bias);
}

__global__ __launch_bounds__(256) void k_conv2(const int* fl, const float* H1,
    const void* g2, const void* bb2, const void* W2, const void* bias2,
    const float* m2, const float* rs2, u16* Fsp){
  __shared__ float xt[Cn*XP];
  if (*fl) conv2_body<1>(H1, g2, bb2, W2, bias2, m2, rs2, Fsp, xt);
  else     conv2_body<0>(H1, g2, bb2, W2, bias2, m2, rs2, Fsp, xt);
}

// -------------------- vector MLP path --------------------
template<int BF>
__device__ __forceinline__ float dotrow(const void* W, int o, const float* v){
  float a0 = 0.f, a1 = 0.f;
  #pragma unroll 4
  for (int k = 0; k < Cn/8; ++k){
    float wv[8]; ld8<BF>(W, o*Cn + k*8, wv);
    const float* vv = v + k*8;
    a0 += wv[0]*vv[0] + wv[1]*vv[1] + wv[2]*vv[2] + wv[3]*vv[3];
    a1 += wv[4]*vv[4] + wv[5]*vv[5] + wv[6]*vv[6] + wv[7]*vv[7];
  }
  return a0 + a1;
}

template<int BF>
__device__ void vec_body(const void* Fv,
    const void* ln1g, const void* ln1b, const void* w1, const void* b1,
    const void* ln2g, const void* ln2b, const void* w2, const void* b2,
    float* Fvp, float* Fvn, float* va, float* red){
  int b = blockIdx.x, tid = threadIdx.x;
  float x0 = ldin<BF>(Fv, b*Cn + tid), x1 = ldin<BF>(Fv, b*Cn + tid + 256);
  float2 r = block_red2(x0 + x1, x0*x0 + x1*x1, red);
  float m = r.x * (1.f/Cn);
  float rv = rsqrtf(r.y * (1.f/Cn) - m*m + 1e-5f);
  va[tid]       = (x0 - m)*rv*ldin<BF>(ln1g, tid)       + ldin<BF>(ln1b, tid);
  va[tid + 256] = (x1 - m)*rv*ldin<BF>(ln1g, tid + 256) + ldin<BF>(ln1b, tid + 256);
  __syncthreads();
  float h0 = fmaxf(dotrow<BF>(w1, tid, va)       + ldin<BF>(b1, tid), 0.f);
  float h1 = fmaxf(dotrow<BF>(w1, tid + 256, va) + ldin<BF>(b1, tid + 256), 0.f);
  r = block_red2(h0 + h1, h0*h0 + h1*h1, red);
  m = r.x * (1.f/Cn);
  rv = rsqrtf(r.y * (1.f/Cn) - m*m + 1e-5f);
  va[tid]       = (h0 - m)*rv*ldin<BF>(ln2g, tid)       + ldin<BF>(ln2b, tid);
  va[tid + 256] = (h1 - m)*rv*ldin<BF>(ln2g, tid + 256) + ldin<BF>(ln2b, tid + 256);
  __syncthreads();
  float y0 = dotrow<BF>(w2, tid, va)       + ldin<BF>(b2, tid);
  float y1 = dotrow<BF>(w2, tid + 256, va) + ldin<BF>(b2, tid + 256);
  Fvp[b*Cn + tid] = y0; Fvp[b*Cn + tid + 256] = y1;
  r = block_red2(y0*y0 + y1*y1, 0.f, red);
  float inv = 1.f / fmaxf(sqrtf(r.x), 1e-12f);
  Fvn[b*Cn + tid] = y0*inv; Fvn[b*Cn + tid + 256] = y1*inv;
}

__global__ __launch_bounds__(256) void k_vec(const int* fl, const void* Fv,
    const void* ln1g, const void* ln1b, const void* w1, const void* b1,
    const void* ln2g, const void* ln2b, const void* w2, const void* b2,
    float* Fvp, float* Fvn){
  __shared__ float va[Cn];
  __shared__ float red[8];
  if (*fl) vec_body<1>(Fv, ln1g, ln1b, w1, b1, ln2g, ln2b, w2, b2, Fvp, Fvn, va, red);
  else     vec_body<0>(Fv, ln1g, ln1b, w1, b1, ln2g, ln2b, w2, b2, Fvp, Fvn, va, red);
}

// -------------------- per-l inverse norms of Ft / prototype -----------------
template<int BF>
__device__ void protonorm_body(const void* Ft, const void* Pr,
                               float* invFt, float* invPr, float* red){
  int l = blockIdx.x, tid = threadIdx.x;
  float a0 = ldin<BF>(Ft, l*Cn + tid), a1 = ldin<BF>(Ft, l*Cn + tid + 256);
  float p0 = ldin<BF>(Pr, l*Cn + tid), p1 = ldin<BF>(Pr, l*Cn + tid + 256);
  float2 r = block_red2(a0*a0 + a1*a1, p0*p0 + p1*p1, red);
  if (tid == 0){
    invFt[l] = 1.f / fmaxf(sqrtf(r.x), 1e-12f);
    invPr[l] = 1.f / fmaxf(sqrtf(r.y), 1e-12f);
  }
}

__global__ __launch_bounds__(256) void k_protonorm(const int* fl, const void* Ft,
    const void* Pr, float* invFt, float* invPr){
  __shared__ float red[8];
  if (*fl) protonorm_body<1>(Ft, Pr, invFt, invPr, red);
  else     protonorm_body<0>(Ft, Pr, invFt, invPr, red);
}

// -------------------- fused dual attention + logits --------------------
#define LT 8       // l-tile
#define LBLK 40    // l per block
#define FP 516     // fsp pitch (floats)

#define EPI(ACC, P, LI) do { \
  float ns = 0.f, dt = 0.f, d1 = 0.f; \
  const float* fr = &ftile[((P)*LT + (LI))*Cn + c0]; \
  float gam = (P) ? gn : gp; \
  _Pragma("unroll") \
  for (int j = 0; j < 8; ++j){ \
    float feat = fmaf(gam, ACC[j], fvp[c0 + j]); \
    float tv = fr[j]; \
    ns = fmaf(feat, feat, ns); dt = fmaf(feat, tv, dt); \
    if (!(P)) d1 = fmaf(fvn[c0 + j], tv, d1); \
  } \
  for (int off = 32; off; off >>= 1){ \
    ns += __shfl_xor(ns, off); dt += __shfl_xor(dt, off); \
    if (!(P)) d1 += __shfl_xor(d1, off); \
  } \
  if (lane == 0){ \
    int l = l0 + (LI); \
    float lgv = dt * invs[(P)*LT + (LI)] / fmaxf(sqrtf(ns), 1e-12f); \
    out[((P) + 1)*BL + b*Ln + l] = lgv; \
    if (!(P)) out[b*Ln + l] = d1 * invs[(LI)]; \
  } \
} while (0)

template<int BF>
__device__ void attn_body(const u16* Fsp, const void* Ft, const void* Pr,
    const float* Fvp_g, const float* Fvn_g,
    const float* invFt, const float* invPr,
    const void* gp_, const void* gn_, float* out,
    float* fsp, float* ftile, float* aw, float* fvp, float* fvn, float* invs){
  int b = blockIdx.y, lg = blockIdx.x;
  int tid = threadIdx.x, lane = tid & 63, wid = tid >> 6;

  const u32* fs2 = (const u32*)(Fsp + (size_t)b*Sn*Cn);
  for (int i = tid; i < Sn*Cn/2; i += 256){
    int s = i >> 8, cp = i & 255;
    u32 u = fs2[i];
    fsp[s*FP + cp*2]     = bflo(u);
    fsp[s*FP + cp*2 + 1] = bfhi(u);
  }
  for (int c = tid; c < Cn; c += 256){ fvp[c] = Fvp_g[b*Cn + c]; fvn[c] = Fvn_g[b*Cn + c]; }
  float gp = ld_gamma(gp_, BF), gn = ld_gamma(gn_, BF);

  for (int t = 0; t < LBLK/LT; ++t){
    int l0 = lg*LBLK + t*LT;
    __syncthreads();   // covers initial staging + ftile/aw/invs reuse
    for (int i = tid; i < 2*LT*Cn; i += 256){
      int p = i >> 12, li = (i >> 9) & (LT - 1), c = i & 511;
      ftile[i] = ldin<BF>(p ? Pr : Ft, (l0 + li)*Cn + c);
    }
    if (tid < 2*LT){
      int p = tid >> 3, li = tid & (LT - 1);
      invs[tid] = (p ? invPr : invFt)[l0 + li];
    }
    __syncthreads();
    // scores: 2*LT*Sn = 784 full-length dots, thread-local
    for (int d = tid; d < 2*LT*Sn; d += 256){
      int s = d % Sn; int q = d / Sn;
      const float* xr = &fsp[s*FP];
      const float* fr = &ftile[q*Cn];
      float a0 = 0.f, a1 = 0.f, a2 = 0.f, a3 = 0.f;
      for (int c = 0; c < Cn; c += 16){
        float4 x0 = *(const float4*)(xr + c);      float4 f0 = *(const float4*)(fr + c);
        float4 x1 = *(const float4*)(xr + c + 4);  float4 f1 = *(const float4*)(fr + c + 4);
        float4 x2 = *(const float4*)(xr + c + 8);  float4 f2 = *(const float4*)(fr + c + 8);
        float4 x3 = *(const float4*)(xr + c + 12); float4 f3 = *(const float4*)(fr + c + 12);
        a0 += x0.x*f0.x + x0.y*f0.y + x0.z*f0.z + x0.w*f0.w;
        a1 += x1.x*f1.x + x1.y*f1.y + x1.z*f1.z + x1.w*f1.w;
        a2 += x2.x*f2.x + x2.y*f2.y + x2.z*f2.z + x2.w*f2.w;
        a3 += x3.x*f3.x + x3.y*f3.y + x3.z*f3.z + x3.w*f3.w;
      }
      aw[q*64 + s] = (a0 + a1) + (a2 + a3);
    }
    __syncthreads();
    // softmax over s (49): one wave per (p,li) job
    for (int j = wid; j < 2*LT; j += 4){
      float x = (lane < Sn) ? aw[j*64 + lane] : -1e30f;
      float mx = x;
      #pragma unroll
      for (int off = 32; off; off >>= 1) mx = fmaxf(mx, __shfl_xor(mx, off));
      float e = (lane < Sn) ? expf(x - mx) : 0.f;
      float sm = e;
      #pragma unroll
      for (int off = 32; off; off >>= 1) sm += __shfl_xor(sm, off);
      if (lane < Sn) aw[j*64 + lane] = e / sm;
    }
    __syncthreads();
    // weighted sums: wave wid owns li in {2*wid, 2*wid+1}, both paths
    int li0 = wid*2;
    int c0 = lane*8;
    float t00[8], t01[8], t10[8], t11[8];
    #pragma unroll
    for (int j = 0; j < 8; ++j){ t00[j] = 0.f; t01[j] = 0.f; t10[j] = 0.f; t11[j] = 0.f; }
    const float* aw00 = &aw[(0*LT + li0)*64];
    const float* aw01 = &aw[(0*LT + li0 + 1)*64];
    const float* aw10 = &aw[(1*LT + li0)*64];
    const float* aw11 = &aw[(1*LT + li0 + 1)*64];
    for (int s = 0; s < Sn; ++s){
      float w00 = aw00[s], w01 = aw01[s], w10 = aw10[s], w11 = aw11[s];
      const float* xr = &fsp[s*FP + c0];
      float4 xa = *(const float4*)(xr);
      float4 xb = *(const float4*)(xr + 4);
      float xv[8] = {xa.x, xa.y, xa.z, xa.w, xb.x, xb.y, xb.z, xb.w};
      #pragma unroll
      for (int j = 0; j < 8; ++j){
        t00[j] = fmaf(w00, xv[j], t00[j]);
        t01[j] = fmaf(w01, xv[j], t01[j]);
        t10[j] = fmaf(w10, xv[j], t10[j]);
        t11[j] = fmaf(w11, xv[j], t11[j]);
      }
    }
    EPI(t00, 0, li0);
    EPI(t01, 0, li0 + 1);
    EPI(t10, 1, li0);
    EPI(t11, 1, li0 + 1);
  }
}

__global__ __launch_bounds__(256) void k_attn(const int* fl, const u16* Fsp,
    const void* Ft, const void* Pr,
    const float* Fvp_g, const float* Fvn_g,
    const float* invFt, const float* invPr,
    const void* gp_, const void* gn_, float* out){
  __shared__ float fsp[Sn*FP];       // 101,136 B
  __shared__ float ftile[2*LT*Cn];   //  32,768 B
  __shared__ float aw[2*LT*64];      //   4,096 B
  __shared__ float fvp[Cn];
  __shared__ float fvn[Cn];
  __shared__ float invs[2*LT];
  if (*fl) attn_body<1>(Fsp, Ft, Pr, Fvp_g, Fvn_g, invFt, invPr, gp_, gn_, out,
                        fsp, ftile, aw, fvp, fvn, invs);
  else     attn_body<0>(Fsp, Ft, Pr, Fvp_g, Fvn_g, invFt, invPr, gp_, gn_, out,
                        fsp, ftile, aw, fvp, fvn, invs);
}

// -------------------- prototype update (deterministic scan) -----------------
template<int BF>
__device__ void proto_body(const int* label, const float* Fvn, const void* Pr,
                           float* out, int* lab){
  int l = blockIdx.x, tid = threadIdx.x;
  if (tid < Bn) lab[tid] = label[tid];
  __syncthreads();
  float4 sum = make_float4(0.f, 0.f, 0.f, 0.f);
  int cnt = 0;
  for (int i = 0; i < Bn; ++i){
    if (lab[i] == l){
      cnt++;
      float4 v = *(const float4*)(Fvn + i*Cn + tid*4);
      sum.x += v.x; sum.y += v.y; sum.z += v.z; sum.w += v.w;
    }
  }
  int base = l*Cn + tid*4;
  float* dst = out + 3*BL + base;
  float sv[4] = {sum.x, sum.y, sum.z, sum.w};
  if (cnt > 0){
    float sc = 0.01f / fmaxf((float)cnt, 1e-8f);
    #pragma unroll
    for (int j = 0; j < 4; ++j)
      dst[j] = 0.99f*ldin<BF>(Pr, base + j) + sv[j]*sc;
  } else {
    #pragma unroll
    for (int j = 0; j < 4; ++j)
      dst[j] = ldin<BF>(Pr, base + j);   // exact pass-through
  }
}

__global__ __launch_bounds__(128) void k_proto(const int* fl, const int* label,
    const float* Fvn, const void* Pr, float* out){
  __shared__ int lab[Bn];
  if (*fl) proto_body<1>(label, Fvn, Pr, out, lab);
  else     proto_body<0>(label, Fvn, Pr, out, lab);
}

// ---------------------------------------------------------------------------
extern "C" void kernel_launch(void* const* d_in, const int* in_sizes, int n_in,
                              void* d_out, int out_size, void* d_ws, size_t ws_size,
                              hipStream_t stream){
  (void)in_sizes; (void)n_in; (void)out_size; (void)ws_size;
  const void* Fs    = d_in[0];
  const void* Ft    = d_in[1];
  const void* Fv    = d_in[2];
  const int*  label = (const int*)d_in[3];
  const void* gn1g  = d_in[4];
  const void* gn1b  = d_in[5];
  const void* c1w   = d_in[6];
  const void* c1b   = d_in[7];
  const void* gn2g  = d_in[8];
  const void* gn2b  = d_in[9];
  const void* c2w   = d_in[10];
  const void* c2b   = d_in[11];
  const void* ln1g  = d_in[12];
  const void* ln1b  = d_in[13];
  const void* l1w   = d_in[14];
  const void* l1b   = d_in[15];
  const void* ln2g  = d_in[16];
  const void* ln2b  = d_in[17];
  const void* l2w   = d_in[18];
  const void* l2b   = d_in[19];
  const void* gp    = d_in[20];
  const void* gnm   = d_in[21];
  const void* proto = d_in[22];
  float* out = (float*)d_out;
  float* ws  = (float*)d_ws;

  float* m1    = ws + 0;
  float* rs1   = ws + 128;
  float* m2    = ws + 256;
  float* rs2   = ws + 384;
  float* invFt = ws + 512;
  float* invPr = ws + 1536;
  int*   iflag = (int*)(ws + 3072);
  float* H1    = ws + 4096;                       // B*C*S f32
  float* Fvp   = H1 + (size_t)Bn*Cn*Sn;           // B*C f32
  float* Fvn   = Fvp + Bn*Cn;                     // B*C f32
  u16*   Fsp   = (u16*)(Fvn + Bn*Cn);             // B*S*C bf16

  k_detect<<<1, 64, 0, stream>>>(Fs, iflag);
  k_gn1_stats<<<Bn, 256, 0, stream>>>(iflag, Fs, m1, rs1);
  k_conv1<<<Bn*2, 256, 0, stream>>>(iflag, Fs, gn1g, gn1b, c1w, c1b, m1, rs1, H1);
  k_gn2_stats<<<Bn, 256, 0, stream>>>(H1, m2, rs2);
  k_conv2<<<Bn*2, 256, 0, stream>>>(iflag, H1, gn2g, gn2b, c2w, c2b, m2, rs2, Fsp);
  k_vec<<<Bn, 256, 0, stream>>>(iflag, Fv, ln1g, ln1b, l1w, l1b, ln2g, ln2b, l2w, l2b, Fvp, Fvn);
  k_protonorm<<<Ln, 256, 0, stream>>>(iflag, Ft, proto, invFt, invPr);
  k_attn<<<dim3(Ln/LBLK, Bn), 256, 0, stream>>>(iflag, Fsp, Ft, proto, Fvp, Fvn,
                                                invFt, invPr, gp, gnm, out);
  k_proto<<<Ln, 128, 0, stream>>>(iflag, label, Fvn, proto, out);
}

// Round 4
// 711.022 us; speedup vs baseline: 2.7511x; 2.7511x over previous
//
#include <hip/hip_runtime.h>

// ---------------------------------------------------------------------------
// DPM_Block — Round 4: MFMA attention (16x16x32 bf16), XOR-swizzled LDS.
// Shapes: B=128, S=49, C=512, L=1000. Inputs f32 (runtime-detected), out f32.
// ws (floats): m1@0 rs1@128 m2@256 rs2@384 invFt@512 invPr@1536 iflag@3072
//   H1 bf16 @4096 (B*C*S) | Fvp f32 | Fvn f32 | Fsp bf16 [b][s][c]
//   | FspT bf16 [b][c][64]  — total ~21.8 MB.
// ---------------------------------------------------------------------------

#define Bn 128
#define Sn 49
#define Cn 512
#define Ln 1000
#define BL (Bn*Ln)

typedef unsigned short u16;
typedef unsigned int u32;

using bfrag = __attribute__((ext_vector_type(8))) short;   // 8 bf16
using ffrag = __attribute__((ext_vector_type(4))) float;   // 4 f32 acc

__device__ __forceinline__ float bf2f(u16 u){ return __uint_as_float(((u32)u) << 16); }
__device__ __forceinline__ float bflo(u32 u){ return __uint_as_float(u << 16); }
__device__ __forceinline__ float bfhi(u32 u){ return __uint_as_float(u & 0xffff0000u); }
__device__ __forceinline__ u16 f2bf(float f){
  u32 x = __float_as_uint(f);
  u32 r = x + 0x7fffu + ((x >> 16) & 1u);   // RNE
  return (u16)(r >> 16);
}

template<int BF>
__device__ __forceinline__ float ldin(const void* p, int i){
  if (BF) return bf2f(((const u16*)p)[i]);
  return ((const float*)p)[i];
}

template<int BF>
__device__ __forceinline__ void ld8(const void* p, int base, float* w){
  if (BF){
    uint4 u = *(const uint4*)((const u16*)p + base);
    w[0]=bflo(u.x); w[1]=bfhi(u.x); w[2]=bflo(u.y); w[3]=bfhi(u.y);
    w[4]=bflo(u.z); w[5]=bfhi(u.z); w[6]=bflo(u.w); w[7]=bfhi(u.w);
  } else {
    float4 a = *(const float4*)((const float*)p + base);
    float4 b = *(const float4*)((const float*)p + base + 4);
    w[0]=a.x; w[1]=a.y; w[2]=a.z; w[3]=a.w;
    w[4]=b.x; w[5]=b.y; w[6]=b.z; w[7]=b.w;
  }
}

__device__ __forceinline__ float ld_gamma(const void* p, int BF){
  float fb = bf2f(((const u16*)p)[0]);
  float ff = ((const float*)p)[0];
  bool pb = (fb > 0.05f && fb < 1.5f);
  bool pf = (ff > 0.05f && ff < 1.5f);
  if (pb && !pf) return fb;
  if (pf && !pb) return ff;
  return BF ? fb : ff;
}

// -------------------- dtype detector --------------------
__global__ void k_detect(const void* Fs, int* flag){
  int lane = threadIdx.x;
  int v = 0;
  for (int i = lane; i < 256; i += 64){
    u16 lo = ((const u16*)Fs)[2*i];
    int e = (lo >> 7) & 0xff;
    v += (e >= 0x70 && e <= 0x8f);
  }
  #pragma unroll
  for (int off = 32; off; off >>= 1) v += __shfl_xor(v, off);
  if (lane == 0) *flag = (v >= 200) ? 1 : 0;
}

__device__ __forceinline__ float2 block_red2(float a, float b, float* scratch){
  __syncthreads();
  #pragma unroll
  for (int off = 32; off; off >>= 1){ a += __shfl_xor(a, off); b += __shfl_xor(b, off); }
  int lane = threadIdx.x & 63, wid = threadIdx.x >> 6;
  if (lane == 0){ scratch[wid] = a; scratch[wid + 4] = b; }
  __syncthreads();
  return make_float2(scratch[0] + scratch[1] + scratch[2] + scratch[3],
                     scratch[4] + scratch[5] + scratch[6] + scratch[7]);
}

// -------------------- groupnorm stats --------------------
template<int BF>
__device__ void gn1_body(const void* Fs, float* m1, float* rs1, float* red){
  int b = blockIdx.x, tid = threadIdx.x;
  float s = 0.f, ss = 0.f;
  for (int i = tid; i < Sn*Cn/8; i += 256){
    float w[8]; ld8<BF>(Fs, b*Sn*Cn + i*8, w);
    #pragma unroll
    for (int j = 0; j < 8; ++j){ s += w[j]; ss += w[j]*w[j]; }
  }
  float2 r = block_red2(s, ss, red);
  if (tid == 0){
    float m = r.x * (1.f/(Sn*Cn));
    float v = r.y * (1.f/(Sn*Cn)) - m*m;
    m1[b] = m; rs1[b] = rsqrtf(v + 1e-5f);
  }
}

__global__ __launch_bounds__(256) void k_gn1_stats(const int* fl, const void* Fs,
                                                   float* m1, float* rs1){
  __shared__ float red[8];
  if (*fl) gn1_body<1>(Fs, m1, rs1, red); else gn1_body<0>(Fs, m1, rs1, red);
}

__global__ __launch_bounds__(256) void k_gn2_stats(const u16* __restrict__ H1,
                                                   float* __restrict__ m2, float* __restrict__ rs2){
  __shared__ float red[8];
  int b = blockIdx.x, tid = threadIdx.x;
  float s = 0.f, ss = 0.f;
  for (int i = tid; i < Sn*Cn/8; i += 256){
    float w[8]; ld8<1>(H1, b*Sn*Cn + i*8, w);
    #pragma unroll
    for (int j = 0; j < 8; ++j){ s += w[j]; ss += w[j]*w[j]; }
  }
  float2 r = block_red2(s, ss, red);
  if (tid == 0){
    float m = r.x * (1.f/(Sn*Cn));
    float v = r.y * (1.f/(Sn*Cn)) - m*m;
    m2[b] = m; rs2[b] = rsqrtf(v + 1e-5f);
  }
}

// -------------------- conv1: GN1 -> W1 -> +bias -> relu -> H1 bf16 ---------
#define XP 52

template<int BF>
__device__ void conv1_body(const void* Fs, const void* g1, const void* bb1,
    const void* W1, const void* bias1,
    const float* m1, const float* rs1, u16* H1, float* xt){
  int b = blockIdx.x >> 1, half = blockIdx.x & 1;
  int tid = threadIdx.x;
  float mean = m1[b], rs = rs1[b];
  for (int i = tid; i < Sn*Cn; i += 256){
    int s = i >> 9, c = i & 511;
    float x = ldin<BF>(Fs, b*Sn*Cn + i);
    xt[c*XP + s] = (x - mean) * rs * ldin<BF>(g1, c) + ldin<BF>(bb1, c);
  }
  __syncthreads();
  int o = half*256 + tid;
  float acc[Sn];
  #pragma unroll
  for (int s = 0; s < Sn; ++s) acc[s] = 0.f;
  for (int k = 0; k < Cn/8; ++k){
    float wv[8]; ld8<BF>(W1, o*Cn + k*8, wv);
    #pragma unroll
    for (int j = 0; j < 8; ++j){
      const float* xr = &xt[(k*8 + j)*XP];
      float w = wv[j];
      #pragma unroll
      for (int s4 = 0; s4 < 48; s4 += 4){
        float4 v = *(const float4*)(xr + s4);
        acc[s4+0] = fmaf(w, v.x, acc[s4+0]);
        acc[s4+1] = fmaf(w, v.y, acc[s4+1]);
        acc[s4+2] = fmaf(w, v.z, acc[s4+2]);
        acc[s4+3] = fmaf(w, v.w, acc[s4+3]);
      }
      acc[48] = fmaf(w, xr[48], acc[48]);
    }
  }
  float bias = ldin<BF>(bias1, o);
  u16* dst = H1 + ((size_t)b*Cn + o)*Sn;
  #pragma unroll
  for (int s = 0; s < Sn; ++s) dst[s] = f2bf(fmaxf(acc[s] + bias, 0.f));
}

__global__ __launch_bounds__(256) void k_conv1(const int* fl, const void* Fs,
    const void* g1, const void* bb1, const void* W1, const void* bias1,
    const float* m1, const float* rs1, u16* H1){
  __shared__ float xt[Cn*XP];
  if (*fl) conv1_body<1>(Fs, g1, bb1, W1, bias1, m1, rs1, H1, xt);
  else     conv1_body<0>(Fs, g1, bb1, W1, bias1, m1, rs1, H1, xt);
}

// ------------- conv2: GN2 -> W2 -> +bias -> Fsp [s][c] + FspT [c][s64] ------
template<int BF>
__device__ void conv2_body(const u16* H1, const void* g2, const void* bb2,
    const void* W2, const void* bias2,
    const float* m2, const float* rs2, u16* Fsp, u16* FspT, float* xt){
  int b = blockIdx.x >> 1, half = blockIdx.x & 1;
  int tid = threadIdx.x;
  float mean = m2[b], rs = rs2[b];
  const u16* src = H1 + (size_t)b*Cn*Sn;
  for (int i = tid; i < Sn*Cn; i += 256){
    int c = i / Sn, s = i - c*Sn;
    xt[c*XP + s] = (bf2f(src[i]) - mean) * rs * ldin<BF>(g2, c) + ldin<BF>(bb2, c);
  }
  __syncthreads();
  int o = half*256 + tid;
  float acc[Sn];
  #pragma unroll
  for (int s = 0; s < Sn; ++s) acc[s] = 0.f;
  for (int k = 0; k < Cn/8; ++k){
    float wv[8]; ld8<BF>(W2, o*Cn + k*8, wv);
    #pragma unroll
    for (int j = 0; j < 8; ++j){
      const float* xr = &xt[(k*8 + j)*XP];
      float w = wv[j];
      #pragma unroll
      for (int s4 = 0; s4 < 48; s4 += 4){
        float4 v = *(const float4*)(xr + s4);
        acc[s4+0] = fmaf(w, v.x, acc[s4+0]);
        acc[s4+1] = fmaf(w, v.y, acc[s4+1]);
        acc[s4+2] = fmaf(w, v.z, acc[s4+2]);
        acc[s4+3] = fmaf(w, v.w, acc[s4+3]);
      }
      acc[48] = fmaf(w, xr[48], acc[48]);
    }
  }
  float bias = ldin<BF>(bias2, o);
  u16 row[64];
  #pragma unroll
  for (int s = 0; s < Sn; ++s) row[s] = f2bf(acc[s] + bias);
  #pragma unroll
  for (int s = Sn; s < 64; ++s) row[s] = 0;
  // transposed copy: contiguous 128B per thread
  uint4* dstT = (uint4*)(FspT + ((size_t)b*Cn + o)*64);
  #pragma unroll
  for (int x = 0; x < 8; ++x) dstT[x] = ((uint4*)row)[x];
  // [s][c] copy (strided)
  u16* dst = Fsp + (size_t)b*Sn*Cn + o;
  #pragma unroll
  for (int s = 0; s < Sn; ++s) dst[s*Cn] = row[s];
}

__global__ __launch_bounds__(256) void k_conv2(const int* fl, const u16* H1,
    const void* g2, const void* bb2, const void* W2, const void* bias2,
    const float* m2, const float* rs2, u16* Fsp, u16* FspT){
  __shared__ float xt[Cn*XP];
  if (*fl) conv2_body<1>(H1, g2, bb2, W2, bias2, m2, rs2, Fsp, FspT, xt);
  else     conv2_body<0>(H1, g2, bb2, W2, bias2, m2, rs2, Fsp, FspT, xt);
}

// -------------------- vector MLP path --------------------
template<int BF>
__device__ __forceinline__ float dotrow(const void* W, int o, const float* v){
  float a0 = 0.f, a1 = 0.f;
  #pragma unroll 4
  for (int k = 0; k < Cn/8; ++k){
    float wv[8]; ld8<BF>(W, o*Cn + k*8, wv);
    const float* vv = v + k*8;
    a0 += wv[0]*vv[0] + wv[1]*vv[1] + wv[2]*vv[2] + wv[3]*vv[3];
    a1 += wv[4]*vv[4] + wv[5]*vv[5] + wv[6]*vv[6] + wv[7]*vv[7];
  }
  return a0 + a1;
}

template<int BF>
__device__ void vec_body(const void* Fv,
    const void* ln1g, const void* ln1b, const void* w1, const void* b1,
    const void* ln2g, const void* ln2b, const void* w2, const void* b2,
    float* Fvp, float* Fvn, float* va, float* red){
  int b = blockIdx.x, tid = threadIdx.x;
  float x0 = ldin<BF>(Fv, b*Cn + tid), x1 = ldin<BF>(Fv, b*Cn + tid + 256);
  float2 r = block_red2(x0 + x1, x0*x0 + x1*x1, red);
  float m = r.x * (1.f/Cn);
  float rv = rsqrtf(r.y * (1.f/Cn) - m*m + 1e-5f);
  va[tid]       = (x0 - m)*rv*ldin<BF>(ln1g, tid)       + ldin<BF>(ln1b, tid);
  va[tid + 256] = (x1 - m)*rv*ldin<BF>(ln1g, tid + 256) + ldin<BF>(ln1b, tid + 256);
  __syncthreads();
  float h0 = fmaxf(dotrow<BF>(w1, tid, va)       + ldin<BF>(b1, tid), 0.f);
  float h1 = fmaxf(dotrow<BF>(w1, tid + 256, va) + ldin<BF>(b1, tid + 256), 0.f);
  r = block_red2(h0 + h1, h0*h0 + h1*h1, red);
  m = r.x * (1.f/Cn);
  rv = rsqrtf(r.y * (1.f/Cn) - m*m + 1e-5f);
  va[tid]       = (h0 - m)*rv*ldin<BF>(ln2g, tid)       + ldin<BF>(ln2b, tid);
  va[tid + 256] = (h1 - m)*rv*ldin<BF>(ln2g, tid + 256) + ldin<BF>(ln2b, tid + 256);
  __syncthreads();
  float y0 = dotrow<BF>(w2, tid, va)       + ldin<BF>(b2, tid);
  float y1 = dotrow<BF>(w2, tid + 256, va) + ldin<BF>(b2, tid + 256);
  Fvp[b*Cn + tid] = y0; Fvp[b*Cn + tid + 256] = y1;
  r = block_red2(y0*y0 + y1*y1, 0.f, red);
  float inv = 1.f / fmaxf(sqrtf(r.x), 1e-12f);
  Fvn[b*Cn + tid] = y0*inv; Fvn[b*Cn + tid + 256] = y1*inv;
}

__global__ __launch_bounds__(256) void k_vec(const int* fl, const void* Fv,
    const void* ln1g, const void* ln1b, const void* w1, const void* b1,
    const void* ln2g, const void* ln2b, const void* w2, const void* b2,
    float* Fvp, float* Fvn){
  __shared__ float va[Cn];
  __shared__ float red[8];
  if (*fl) vec_body<1>(Fv, ln1g, ln1b, w1, b1, ln2g, ln2b, w2, b2, Fvp, Fvn, va, red);
  else     vec_body<0>(Fv, ln1g, ln1b, w1, b1, ln2g, ln2b, w2, b2, Fvp, Fvn, va, red);
}

// -------------------- per-l inverse norms -----------------
template<int BF>
__device__ void protonorm_body(const void* Ft, const void* Pr,
                               float* invFt, float* invPr, float* red){
  int l = blockIdx.x, tid = threadIdx.x;
  float a0 = ldin<BF>(Ft, l*Cn + tid), a1 = ldin<BF>(Ft, l*Cn + tid + 256);
  float p0 = ldin<BF>(Pr, l*Cn + tid), p1 = ldin<BF>(Pr, l*Cn + tid + 256);
  float2 r = block_red2(a0*a0 + a1*a1, p0*p0 + p1*p1, red);
  if (tid == 0){
    invFt[l] = 1.f / fmaxf(sqrtf(r.x), 1e-12f);
    invPr[l] = 1.f / fmaxf(sqrtf(r.y), 1e-12f);
  }
}

__global__ __launch_bounds__(256) void k_protonorm(const int* fl, const void* Ft,
    const void* Pr, float* invFt, float* invPr){
  __shared__ float red[8];
  if (*fl) protonorm_body<1>(Ft, Pr, invFt, invPr, red);
  else     protonorm_body<0>(Ft, Pr, invFt, invPr, red);
}

// -------------------- MFMA fused dual attention + logits --------------------
// block: one b, 128 l. LDS: fsp_sc [64][512] bf16 swz, fsp_cs [512][64] bf16
// swz, ftile [16][512] bf16 swz, aw [16][68] f32, a1 [16][64] bf16,
// fvp/fvn [512] f32, epi [16][4][4] f32. Total 158,976 B.
template<int BF>
__device__ void attn2_body(const u16* __restrict__ Fsp_g, const u16* __restrict__ FspT_g,
    const void* Ft, const void* Pr,
    const float* Fvp_g, const float* Fvn_g,
    const float* invFt, const float* invPr,
    const void* gp_, const void* gn_, float* out,
    u16* fsp_sc, u16* fsp_cs, u16* ftile, float* aw, u16* a1,
    float* fvp, float* fvn, float* epi){
  int b = blockIdx.y, lg = blockIdx.x;
  int tid = threadIdx.x, lane = tid & 63, wid = tid >> 6;
  int lq = lane & 15, g4 = lane >> 4;

  // stage Fsp [s][c], rows >=49 zero; slot swizzle j^(s&7)
  const u16* fsg = Fsp_g + (size_t)b*Sn*Cn;
  for (int idx = tid; idx < 64*64; idx += 256){
    int s = idx >> 6, j = idx & 63;
    uint4 v = {0,0,0,0};
    if (s < Sn) v = *(const uint4*)(fsg + s*Cn + j*8);
    *(uint4*)(fsp_sc + (((s<<6) + (j ^ (s&7)))<<3)) = v;
  }
  // stage FspT [c][s64]; slot swizzle j^(c&7)
  const u16* ftg = FspT_g + (size_t)b*Cn*64;
  for (int idx = tid; idx < Cn*8; idx += 256){
    int c = idx >> 3, j = idx & 7;
    uint4 v = *(const uint4*)(ftg + (c<<6) + j*8);
    *(uint4*)(fsp_cs + (((c<<3) + (j ^ (c&7)))<<3)) = v;
  }
  for (int c = tid; c < Cn; c += 256){ fvp[c] = Fvp_g[b*Cn + c]; fvn[c] = Fvn_g[b*Cn + c]; }
  float gp = ld_gamma(gp_, BF), gn = ld_gamma(gn_, BF);

  for (int t = 0; t < 8; ++t){
    int l0t = lg*128 + t*16;
    for (int p = 0; p < 2; ++p){
      const void* Tsrc = p ? Pr : Ft;
      float gam = p ? gn : gp;
      // stage ftile [q][c] bf16, swz j^(q&7); zero rows for l>=Ln
      for (int idx = tid; idx < 1024; idx += 256){
        int q = idx >> 6, j = idx & 63;
        int l = l0t + q;
        uint4 v = {0,0,0,0};
        if (l < Ln){
          float w[8]; ld8<BF>(Tsrc, l*Cn + j*8, w);
          v.x = (u32)f2bf(w[0]) | ((u32)f2bf(w[1])<<16);
          v.y = (u32)f2bf(w[2]) | ((u32)f2bf(w[3])<<16);
          v.z = (u32)f2bf(w[4]) | ((u32)f2bf(w[5])<<16);
          v.w = (u32)f2bf(w[6]) | ((u32)f2bf(w[7])<<16);
        }
        *(uint4*)(ftile + (((q<<6) + (j ^ (q&7)))<<3)) = v;
      }
      __syncthreads();   // #1: ftile (and initial staging) ready
      // phase A: scores D[q, s], wave wid owns s-tile st=wid
      {
        ffrag acc = {0.f, 0.f, 0.f, 0.f};
        int s = wid*16 + lq;
        #pragma unroll
        for (int kb = 0; kb < 16; ++kb){
          int j = kb*4 + g4;
          bfrag af = *(const bfrag*)(ftile + (((lq<<6) + (j ^ (lq&7)))<<3));
          bfrag bf_ = *(const bfrag*)(fsp_sc + (((s<<6) + (j ^ (s&7)))<<3));
          acc = __builtin_amdgcn_mfma_f32_16x16x32_bf16(af, bf_, acc, 0, 0, 0);
        }
        #pragma unroll
        for (int r = 0; r < 4; ++r)
          aw[(g4*4 + r)*68 + wid*16 + lq] = acc[r];
      }
      __syncthreads();   // #2: scores ready
      // softmax over s (49 real), rows q = wid*4+rr
      #pragma unroll
      for (int rr = 0; rr < 4; ++rr){
        int q = wid*4 + rr;
        float x = (lane < Sn) ? aw[q*68 + lane] : -1e30f;
        float mx = x;
        #pragma unroll
        for (int m = 32; m; m >>= 1) mx = fmaxf(mx, __shfl_xor(mx, m));
        float e = (lane < Sn) ? expf(x - mx) : 0.f;
        float sm = e;
        #pragma unroll
        for (int m = 32; m; m >>= 1) sm += __shfl_xor(sm, m);
        a1[(q<<6) + lane] = f2bf(e / sm);   // lanes 49..63 write 0
      }
      __syncthreads();   // #3: a1 ready
      // phase C: feat D[q, c] + fused epilogue; wave owns 8 c-tiles
      {
        bfrag a1f0 = *(const bfrag*)(a1 + (lq<<6) + ((0*4 + g4)<<3));
        bfrag a1f1 = *(const bfrag*)(a1 + (lq<<6) + ((1*4 + g4)<<3));
        float ns[4] = {0,0,0,0}, dt[4] = {0,0,0,0}, d1[4] = {0,0,0,0};
        #pragma unroll
        for (int cc = 0; cc < 8; ++cc){
          int c_ = ((wid*8 + cc)<<4) + lq;
          ffrag a2 = {0.f, 0.f, 0.f, 0.f};
          bfrag b0 = *(const bfrag*)(fsp_cs + (((c_<<3) + ((0*4 + g4) ^ (c_&7)))<<3));
          a2 = __builtin_amdgcn_mfma_f32_16x16x32_bf16(a1f0, b0, a2, 0, 0, 0);
          bfrag b1 = *(const bfrag*)(fsp_cs + (((c_<<3) + ((1*4 + g4) ^ (c_&7)))<<3));
          a2 = __builtin_amdgcn_mfma_f32_16x16x32_bf16(a1f1, b1, a2, 0, 0, 0);
          float fp = fvp[c_], fn = fvn[c_];
          #pragma unroll
          for (int r = 0; r < 4; ++r){
            int q = g4*4 + r;
            float tv = bf2f(ftile[(q<<9) + ((((c_>>3) ^ (q&7)))<<3) + (c_&7)]);
            float feat = fmaf(gam, a2[r], fp);
            ns[r] = fmaf(feat, feat, ns[r]);
            dt[r] = fmaf(feat, tv, dt[r]);
            d1[r] = fmaf(fn, tv, d1[r]);
          }
        }
        #pragma unroll
        for (int m = 1; m <= 8; m <<= 1){
          #pragma unroll
          for (int r = 0; r < 4; ++r){
            ns[r] += __shfl_xor(ns[r], m);
            dt[r] += __shfl_xor(dt[r], m);
            d1[r] += __shfl_xor(d1[r], m);
          }
        }
        if (lq == 0){
          #pragma unroll
          for (int r = 0; r < 4; ++r){
            int q = g4*4 + r;
            epi[((q<<2) + wid)*4 + 0] = ns[r];
            epi[((q<<2) + wid)*4 + 1] = dt[r];
            epi[((q<<2) + wid)*4 + 2] = d1[r];
          }
        }
      }
      __syncthreads();   // #4: epi ready
      if (wid == 0){
        int q = lane >> 2, w = lane & 3;
        float e0 = epi[((q<<2) + w)*4 + 0];
        float e1 = epi[((q<<2) + w)*4 + 1];
        float e2 = epi[((q<<2) + w)*4 + 2];
        e0 += __shfl_xor(e0, 1); e0 += __shfl_xor(e0, 2);
        e1 += __shfl_xor(e1, 1); e1 += __shfl_xor(e1, 2);
        e2 += __shfl_xor(e2, 1); e2 += __shfl_xor(e2, 2);
        int l = l0t + q;
        if (w == 0 && l < Ln){
          float inv = p ? invPr[l] : invFt[l];
          out[(size_t)(p+1)*BL + (size_t)b*Ln + l] = e1 * inv / fmaxf(sqrtf(e0), 1e-12f);
          if (p == 0) out[(size_t)b*Ln + l] = e2 * inv;
        }
      }
      // no barrier needed: next phase writes only ftile (reads done pre-#4),
      // and wave0 passes #1' before anyone touches aw/a1/epi again.
    }
  }
}

__global__ __launch_bounds__(256) void k_attn2(const int* fl,
    const u16* Fsp_g, const u16* FspT_g, const void* Ft, const void* Pr,
    const float* Fvp_g, const float* Fvn_g,
    const float* invFt, const float* invPr,
    const void* gp_, const void* gn_, float* out){
  __shared__ u16 fsp_sc[64*512];    // 65536 B
  __shared__ u16 fsp_cs[512*64];    // 65536 B
  __shared__ u16 ftile[16*512];     // 16384 B
  __shared__ float aw[16*68];       //  4352 B
  __shared__ u16 a1[16*64];         //  2048 B
  __shared__ float fvp[Cn];         //  2048 B
  __shared__ float fvn[Cn];         //  2048 B
  __shared__ float epi[16*4*4];     //  1024 B
  if (*fl) attn2_body<1>(Fsp_g, FspT_g, Ft, Pr, Fvp_g, Fvn_g, invFt, invPr,
                         gp_, gn_, out, fsp_sc, fsp_cs, ftile, aw, a1, fvp, fvn, epi);
  else     attn2_body<0>(Fsp_g, FspT_g, Ft, Pr, Fvp_g, Fvn_g, invFt, invPr,
                         gp_, gn_, out, fsp_sc, fsp_cs, ftile, aw, a1, fvp, fvn, epi);
}

// -------------------- prototype update (deterministic scan) -----------------
template<int BF>
__device__ void proto_body(const int* label, const float* Fvn, const void* Pr,
                           float* out, int* lab){
  int l = blockIdx.x, tid = threadIdx.x;
  if (tid < Bn) lab[tid] = label[tid];
  __syncthreads();
  float4 sum = make_float4(0.f, 0.f, 0.f, 0.f);
  int cnt = 0;
  for (int i = 0; i < Bn; ++i){
    if (lab[i] == l){
      cnt++;
      float4 v = *(const float4*)(Fvn + i*Cn + tid*4);
      sum.x += v.x; sum.y += v.y; sum.z += v.z; sum.w += v.w;
    }
  }
  int base = l*Cn + tid*4;
  float* dst = out + 3*BL + base;
  float sv[4] = {sum.x, sum.y, sum.z, sum.w};
  if (cnt > 0){
    float sc = 0.01f / fmaxf((float)cnt, 1e-8f);
    #pragma unroll
    for (int j = 0; j < 4; ++j)
      dst[j] = 0.99f*ldin<BF>(Pr, base + j) + sv[j]*sc;
  } else {
    #pragma unroll
    for (int j = 0; j < 4; ++j)
      dst[j] = ldin<BF>(Pr, base + j);
  }
}

__global__ __launch_bounds__(128) void k_proto(const int* fl, const int* label,
    const float* Fvn, const void* Pr, float* out){
  __shared__ int lab[Bn];
  if (*fl) proto_body<1>(label, Fvn, Pr, out, lab);
  else     proto_body<0>(label, Fvn, Pr, out, lab);
}

// ---------------------------------------------------------------------------
extern "C" void kernel_launch(void* const* d_in, const int* in_sizes, int n_in,
                              void* d_out, int out_size, void* d_ws, size_t ws_size,
                              hipStream_t stream){
  (void)in_sizes; (void)n_in; (void)out_size; (void)ws_size;
  const void* Fs    = d_in[0];
  const void* Ft    = d_in[1];
  const void* Fv    = d_in[2];
  const int*  label = (const int*)d_in[3];
  const void* gn1g  = d_in[4];
  const void* gn1b  = d_in[5];
  const void* c1w   = d_in[6];
  const void* c1b   = d_in[7];
  const void* gn2g  = d_in[8];
  const void* gn2b  = d_in[9];
  const void* c2w   = d_in[10];
  const void* c2b   = d_in[11];
  const void* ln1g  = d_in[12];
  const void* ln1b  = d_in[13];
  const void* l1w   = d_in[14];
  const void* l1b   = d_in[15];
  const void* ln2g  = d_in[16];
  const void* ln2b  = d_in[17];
  const void* l2w   = d_in[18];
  const void* l2b   = d_in[19];
  const void* gp    = d_in[20];
  const void* gnm   = d_in[21];
  const void* proto = d_in[22];
  float* out = (float*)d_out;
  float* ws  = (float*)d_ws;

  float* m1    = ws + 0;
  float* rs1   = ws + 128;
  float* m2    = ws + 256;
  float* rs2   = ws + 384;
  float* invFt = ws + 512;
  float* invPr = ws + 1536;
  int*   iflag = (int*)(ws + 3072);
  u16*   H1    = (u16*)(ws + 4096);                   // B*C*S bf16
  float* Fvp   = ws + 4096 + (size_t)Bn*Cn*Sn/2;      // B*C f32
  float* Fvn   = Fvp + Bn*Cn;                         // B*C f32
  u16*   Fsp   = (u16*)(Fvn + Bn*Cn);                 // B*S*C bf16
  u16*   FspT  = Fsp + (size_t)Bn*Sn*Cn;              // B*C*64 bf16

  k_detect<<<1, 64, 0, stream>>>(Fs, iflag);
  k_gn1_stats<<<Bn, 256, 0, stream>>>(iflag, Fs, m1, rs1);
  k_conv1<<<Bn*2, 256, 0, stream>>>(iflag, Fs, gn1g, gn1b, c1w, c1b, m1, rs1, H1);
  k_gn2_stats<<<Bn, 256, 0, stream>>>(H1, m2, rs2);
  k_conv2<<<Bn*2, 256, 0, stream>>>(iflag, H1, gn2g, gn2b, c2w, c2b, m2, rs2, Fsp, FspT);
  k_vec<<<Bn, 256, 0, stream>>>(iflag, Fv, ln1g, ln1b, l1w, l1b, ln2g, ln2b, l2w, l2b, Fvp, Fvn);
  k_protonorm<<<Ln, 256, 0, stream>>>(iflag, Ft, proto, invFt, invPr);
  k_attn2<<<dim3(8, Bn), 256, 0, stream>>>(iflag, Fsp, FspT, Ft, proto, Fvp, Fvn,
                                           invFt, invPr, gp, gnm, out);
  k_proto<<<Ln, 128, 0, stream>>>(iflag, label, Fvn, proto, out);
}

// Round 5
// 522.785 us; speedup vs baseline: 3.7416x; 1.3601x over previous
//
#include <hip/hip_runtime.h>

// ---------------------------------------------------------------------------
// DPM_Block — Round 5: score-space attention. feat tensor never materialized:
//   feat·Ft = gam*sum(a1*raw) + aug-col-56;  |feat|^2 = gam^2*a1'Ga1 + 2gam*wv + fvpSq
// FspAug[b][64][512] bf16 (rows 0-48 Fsp, 56=fvp, 57=fvn, rest 0);
// G[b][64][64] bf16 gram; FtB/PrB bf16 [1024][512] zero-padded.
// ---------------------------------------------------------------------------

#define Bn 128
#define Sn 49
#define Cn 512
#define Ln 1000
#define BL (Bn*Ln)

typedef unsigned short u16;
typedef unsigned int u32;

using bfrag = __attribute__((ext_vector_type(8))) short;   // 8 bf16 (4 VGPR)
using ffrag = __attribute__((ext_vector_type(4))) float;   // 4 f32 acc

__device__ __forceinline__ float bf2f(u16 u){ return __uint_as_float(((u32)u) << 16); }
__device__ __forceinline__ float bflo(u32 u){ return __uint_as_float(u << 16); }
__device__ __forceinline__ float bfhi(u32 u){ return __uint_as_float(u & 0xffff0000u); }
__device__ __forceinline__ u16 f2bf(float f){
  u32 x = __float_as_uint(f);
  u32 r = x + 0x7fffu + ((x >> 16) & 1u);   // RNE
  return (u16)(r >> 16);
}

template<int BF>
__device__ __forceinline__ float ldin(const void* p, int i){
  if (BF) return bf2f(((const u16*)p)[i]);
  return ((const float*)p)[i];
}

template<int BF>
__device__ __forceinline__ void ld8(const void* p, int base, float* w){
  if (BF){
    uint4 u = *(const uint4*)((const u16*)p + base);
    w[0]=bflo(u.x); w[1]=bfhi(u.x); w[2]=bflo(u.y); w[3]=bfhi(u.y);
    w[4]=bflo(u.z); w[5]=bfhi(u.z); w[6]=bflo(u.w); w[7]=bfhi(u.w);
  } else {
    float4 a = *(const float4*)((const float*)p + base);
    float4 b = *(const float4*)((const float*)p + base + 4);
    w[0]=a.x; w[1]=a.y; w[2]=a.z; w[3]=a.w;
    w[4]=b.x; w[5]=b.y; w[6]=b.z; w[7]=b.w;
  }
}

__device__ __forceinline__ float ld_gamma(const void* p, int BF){
  float fb = bf2f(((const u16*)p)[0]);
  float ff = ((const float*)p)[0];
  bool pb = (fb > 0.05f && fb < 1.5f);
  bool pf = (ff > 0.05f && ff < 1.5f);
  if (pb && !pf) return fb;
  if (pf && !pb) return ff;
  return BF ? fb : ff;
}

// -------------------- dtype detector --------------------
__global__ void k_detect(const void* Fs, int* flag){
  int lane = threadIdx.x;
  int v = 0;
  for (int i = lane; i < 256; i += 64){
    u16 lo = ((const u16*)Fs)[2*i];
    int e = (lo >> 7) & 0xff;
    v += (e >= 0x70 && e <= 0x8f);
  }
  #pragma unroll
  for (int off = 32; off; off >>= 1) v += __shfl_xor(v, off);
  if (lane == 0) *flag = (v >= 200) ? 1 : 0;
}

__device__ __forceinline__ float2 block_red2(float a, float b, float* scratch){
  __syncthreads();
  #pragma unroll
  for (int off = 32; off; off >>= 1){ a += __shfl_xor(a, off); b += __shfl_xor(b, off); }
  int lane = threadIdx.x & 63, wid = threadIdx.x >> 6;
  if (lane == 0){ scratch[wid] = a; scratch[wid + 4] = b; }
  __syncthreads();
  return make_float2(scratch[0] + scratch[1] + scratch[2] + scratch[3],
                     scratch[4] + scratch[5] + scratch[6] + scratch[7]);
}

// -------------------- groupnorm stats --------------------
template<int BF>
__device__ void gn1_body(const void* Fs, float* m1, float* rs1, float* red){
  int b = blockIdx.x, tid = threadIdx.x;
  float s = 0.f, ss = 0.f;
  for (int i = tid; i < Sn*Cn/8; i += 256){
    float w[8]; ld8<BF>(Fs, b*Sn*Cn + i*8, w);
    #pragma unroll
    for (int j = 0; j < 8; ++j){ s += w[j]; ss += w[j]*w[j]; }
  }
  float2 r = block_red2(s, ss, red);
  if (tid == 0){
    float m = r.x * (1.f/(Sn*Cn));
    float v = r.y * (1.f/(Sn*Cn)) - m*m;
    m1[b] = m; rs1[b] = rsqrtf(v + 1e-5f);
  }
}

__global__ __launch_bounds__(256) void k_gn1_stats(const int* fl, const void* Fs,
                                                   float* m1, float* rs1){
  __shared__ float red[8];
  if (*fl) gn1_body<1>(Fs, m1, rs1, red); else gn1_body<0>(Fs, m1, rs1, red);
}

__global__ __launch_bounds__(256) void k_gn2_stats(const u16* __restrict__ H1,
                                                   float* __restrict__ m2, float* __restrict__ rs2){
  __shared__ float red[8];
  int b = blockIdx.x, tid = threadIdx.x;
  float s = 0.f, ss = 0.f;
  for (int i = tid; i < Sn*Cn/8; i += 256){
    float w[8]; ld8<1>(H1, b*Sn*Cn + i*8, w);
    #pragma unroll
    for (int j = 0; j < 8; ++j){ s += w[j]; ss += w[j]*w[j]; }
  }
  float2 r = block_red2(s, ss, red);
  if (tid == 0){
    float m = r.x * (1.f/(Sn*Cn));
    float v = r.y * (1.f/(Sn*Cn)) - m*m;
    m2[b] = m; rs2[b] = rsqrtf(v + 1e-5f);
  }
}

// -------------------- conv1: GN1 -> W1 -> +bias -> relu -> H1 bf16 ---------
#define XP 52

template<int BF>
__device__ void conv1_body(const void* Fs, const void* g1, const void* bb1,
    const void* W1, const void* bias1,
    const float* m1, const float* rs1, u16* H1, float* xt){
  int b = blockIdx.x >> 1, half = blockIdx.x & 1;
  int tid = threadIdx.x;
  float mean = m1[b], rs = rs1[b];
  for (int i = tid; i < Sn*Cn; i += 256){
    int s = i >> 9, c = i & 511;
    float x = ldin<BF>(Fs, b*Sn*Cn + i);
    xt[c*XP + s] = (x - mean) * rs * ldin<BF>(g1, c) + ldin<BF>(bb1, c);
  }
  __syncthreads();
  int o = half*256 + tid;
  float acc[Sn];
  #pragma unroll
  for (int s = 0; s < Sn; ++s) acc[s] = 0.f;
  for (int k = 0; k < Cn/8; ++k){
    float wv[8]; ld8<BF>(W1, o*Cn + k*8, wv);
    #pragma unroll
    for (int j = 0; j < 8; ++j){
      const float* xr = &xt[(k*8 + j)*XP];
      float w = wv[j];
      #pragma unroll
      for (int s4 = 0; s4 < 48; s4 += 4){
        float4 v = *(const float4*)(xr + s4);
        acc[s4+0] = fmaf(w, v.x, acc[s4+0]);
        acc[s4+1] = fmaf(w, v.y, acc[s4+1]);
        acc[s4+2] = fmaf(w, v.z, acc[s4+2]);
        acc[s4+3] = fmaf(w, v.w, acc[s4+3]);
      }
      acc[48] = fmaf(w, xr[48], acc[48]);
    }
  }
  float bias = ldin<BF>(bias1, o);
  u16* dst = H1 + ((size_t)b*Cn + o)*Sn;
  #pragma unroll
  for (int s = 0; s < Sn; ++s) dst[s] = f2bf(fmaxf(acc[s] + bias, 0.f));
}

__global__ __launch_bounds__(256) void k_conv1(const int* fl, const void* Fs,
    const void* g1, const void* bb1, const void* W1, const void* bias1,
    const float* m1, const float* rs1, u16* H1){
  __shared__ float xt[Cn*XP];
  if (*fl) conv1_body<1>(Fs, g1, bb1, W1, bias1, m1, rs1, H1, xt);
  else     conv1_body<0>(Fs, g1, bb1, W1, bias1, m1, rs1, H1, xt);
}

// ------------- conv2: GN2 -> W2 -> +bias -> FspAug rows 0..48 (+zero 49..63)
template<int BF>
__device__ void conv2_body(const u16* H1, const void* g2, const void* bb2,
    const void* W2, const void* bias2,
    const float* m2, const float* rs2, u16* FspAug, float* xt){
  int b = blockIdx.x >> 1, half = blockIdx.x & 1;
  int tid = threadIdx.x;
  float mean = m2[b], rs = rs2[b];
  const u16* src = H1 + (size_t)b*Cn*Sn;
  for (int i = tid; i < Sn*Cn; i += 256){
    int c = i / Sn, s = i - c*Sn;
    xt[c*XP + s] = (bf2f(src[i]) - mean) * rs * ldin<BF>(g2, c) + ldin<BF>(bb2, c);
  }
  __syncthreads();
  int o = half*256 + tid;
  float acc[Sn];
  #pragma unroll
  for (int s = 0; s < Sn; ++s) acc[s] = 0.f;
  for (int k = 0; k < Cn/8; ++k){
    float wv[8]; ld8<BF>(W2, o*Cn + k*8, wv);
    #pragma unroll
    for (int j = 0; j < 8; ++j){
      const float* xr = &xt[(k*8 + j)*XP];
      float w = wv[j];
      #pragma unroll
      for (int s4 = 0; s4 < 48; s4 += 4){
        float4 v = *(const float4*)(xr + s4);
        acc[s4+0] = fmaf(w, v.x, acc[s4+0]);
        acc[s4+1] = fmaf(w, v.y, acc[s4+1]);
        acc[s4+2] = fmaf(w, v.z, acc[s4+2]);
        acc[s4+3] = fmaf(w, v.w, acc[s4+3]);
      }
      acc[48] = fmaf(w, xr[48], acc[48]);
    }
  }
  float bias = ldin<BF>(bias2, o);
  u16* dst = FspAug + (size_t)b*64*512 + o;
  #pragma unroll
  for (int s = 0; s < Sn; ++s) dst[s*512] = f2bf(acc[s] + bias);
  #pragma unroll
  for (int s = Sn; s < 64; ++s) dst[s*512] = 0;   // zero pad rows (incl 56/57, fixed by k_prep)
}

__global__ __launch_bounds__(256) void k_conv2(const int* fl, const u16* H1,
    const void* g2, const void* bb2, const void* W2, const void* bias2,
    const float* m2, const float* rs2, u16* FspAug){
  __shared__ float xt[Cn*XP];
  if (*fl) conv2_body<1>(H1, g2, bb2, W2, bias2, m2, rs2, FspAug, xt);
  else     conv2_body<0>(H1, g2, bb2, W2, bias2, m2, rs2, FspAug, xt);
}

// -------------------- vector MLP path --------------------
template<int BF>
__device__ __forceinline__ float dotrow(const void* W, int o, const float* v){
  float a0 = 0.f, a1 = 0.f;
  #pragma unroll 4
  for (int k = 0; k < Cn/8; ++k){
    float wv[8]; ld8<BF>(W, o*Cn + k*8, wv);
    const float* vv = v + k*8;
    a0 += wv[0]*vv[0] + wv[1]*vv[1] + wv[2]*vv[2] + wv[3]*vv[3];
    a1 += wv[4]*vv[4] + wv[5]*vv[5] + wv[6]*vv[6] + wv[7]*vv[7];
  }
  return a0 + a1;
}

template<int BF>
__device__ void vec_body(const void* Fv,
    const void* ln1g, const void* ln1b, const void* w1, const void* b1,
    const void* ln2g, const void* ln2b, const void* w2, const void* b2,
    float* Fvp, float* Fvn, float* va, float* red){
  int b = blockIdx.x, tid = threadIdx.x;
  float x0 = ldin<BF>(Fv, b*Cn + tid), x1 = ldin<BF>(Fv, b*Cn + tid + 256);
  float2 r = block_red2(x0 + x1, x0*x0 + x1*x1, red);
  float m = r.x * (1.f/Cn);
  float rv = rsqrtf(r.y * (1.f/Cn) - m*m + 1e-5f);
  va[tid]       = (x0 - m)*rv*ldin<BF>(ln1g, tid)       + ldin<BF>(ln1b, tid);
  va[tid + 256] = (x1 - m)*rv*ldin<BF>(ln1g, tid + 256) + ldin<BF>(ln1b, tid + 256);
  __syncthreads();
  float h0 = fmaxf(dotrow<BF>(w1, tid, va)       + ldin<BF>(b1, tid), 0.f);
  float h1 = fmaxf(dotrow<BF>(w1, tid + 256, va) + ldin<BF>(b1, tid + 256), 0.f);
  r = block_red2(h0 + h1, h0*h0 + h1*h1, red);
  m = r.x * (1.f/Cn);
  rv = rsqrtf(r.y * (1.f/Cn) - m*m + 1e-5f);
  va[tid]       = (h0 - m)*rv*ldin<BF>(ln2g, tid)       + ldin<BF>(ln2b, tid);
  va[tid + 256] = (h1 - m)*rv*ldin<BF>(ln2g, tid + 256) + ldin<BF>(ln2b, tid + 256);
  __syncthreads();
  float y0 = dotrow<BF>(w2, tid, va)       + ldin<BF>(b2, tid);
  float y1 = dotrow<BF>(w2, tid + 256, va) + ldin<BF>(b2, tid + 256);
  Fvp[b*Cn + tid] = y0; Fvp[b*Cn + tid + 256] = y1;
  r = block_red2(y0*y0 + y1*y1, 0.f, red);
  float inv = 1.f / fmaxf(sqrtf(r.x), 1e-12f);
  Fvn[b*Cn + tid] = y0*inv; Fvn[b*Cn + tid + 256] = y1*inv;
}

__global__ __launch_bounds__(256) void k_vec(const int* fl, const void* Fv,
    const void* ln1g, const void* ln1b, const void* w1, const void* b1,
    const void* ln2g, const void* ln2b, const void* w2, const void* b2,
    float* Fvp, float* Fvn){
  __shared__ float va[Cn];
  __shared__ float red[8];
  if (*fl) vec_body<1>(Fv, ln1g, ln1b, w1, b1, ln2g, ln2b, w2, b2, Fvp, Fvn, va, red);
  else     vec_body<0>(Fv, ln1g, ln1b, w1, b1, ln2g, ln2b, w2, b2, Fvp, Fvn, va, red);
}

// ------------- per-l inverse norms + bf16 copies of Ft / prototype ----------
template<int BF>
__device__ void protonorm_body(const void* Ft, const void* Pr,
                               float* invFt, float* invPr,
                               u16* FtB, u16* PrB, float* red){
  int l = blockIdx.x, tid = threadIdx.x;
  if (l >= Ln){
    FtB[(size_t)l*512 + tid] = 0; FtB[(size_t)l*512 + tid + 256] = 0;
    PrB[(size_t)l*512 + tid] = 0; PrB[(size_t)l*512 + tid + 256] = 0;
    return;
  }
  float a0 = ldin<BF>(Ft, l*Cn + tid), a1 = ldin<BF>(Ft, l*Cn + tid + 256);
  float p0 = ldin<BF>(Pr, l*Cn + tid), p1 = ldin<BF>(Pr, l*Cn + tid + 256);
  FtB[(size_t)l*512 + tid] = f2bf(a0); FtB[(size_t)l*512 + tid + 256] = f2bf(a1);
  PrB[(size_t)l*512 + tid] = f2bf(p0); PrB[(size_t)l*512 + tid + 256] = f2bf(p1);
  float2 r = block_red2(a0*a0 + a1*a1, p0*p0 + p1*p1, red);
  if (tid == 0){
    invFt[l] = 1.f / fmaxf(sqrtf(r.x), 1e-12f);
    invPr[l] = 1.f / fmaxf(sqrtf(r.y), 1e-12f);
  }
}

__global__ __launch_bounds__(256) void k_protonorm(const int* fl, const void* Ft,
    const void* Pr, float* invFt, float* invPr, u16* FtB, u16* PrB){
  __shared__ float red[8];
  if (*fl) protonorm_body<1>(Ft, Pr, invFt, invPr, FtB, PrB, red);
  else     protonorm_body<0>(Ft, Pr, invFt, invPr, FtB, PrB, red);
}

// ------------- k_prep: aug rows 56/57 <- fvp/fvn; G = Aug·Aug^T (MFMA) ------
__global__ __launch_bounds__(256) void k_prep(const float* __restrict__ Fvp,
    const float* __restrict__ Fvn, u16* __restrict__ FspAug, u16* __restrict__ Gb){
  __shared__ u16 xa[64*512];   // 64 KiB, swizzled
  int b = blockIdx.x, tid = threadIdx.x;
  int lane = tid & 63, wid = tid >> 6, lq = lane & 15, g4 = lane >> 4;
  for (int idx = tid; idx < 64*64; idx += 256){
    int s = idx >> 6, j = idx & 63;
    uint4 v;
    if (s == 56 || s == 57){
      const float* src = (s == 56 ? Fvp : Fvn) + b*512 + j*8;
      float w[8];
      #pragma unroll
      for (int k = 0; k < 8; ++k) w[k] = src[k];
      v.x = (u32)f2bf(w[0]) | ((u32)f2bf(w[1]) << 16);
      v.y = (u32)f2bf(w[2]) | ((u32)f2bf(w[3]) << 16);
      v.z = (u32)f2bf(w[4]) | ((u32)f2bf(w[5]) << 16);
      v.w = (u32)f2bf(w[6]) | ((u32)f2bf(w[7]) << 16);
      *(uint4*)(FspAug + ((size_t)(b*64 + s))*512 + j*8) = v;   // publish for attn B-frags
    } else {
      v = *(const uint4*)(FspAug + ((size_t)(b*64 + s))*512 + j*8);
    }
    *(uint4*)(xa + s*512 + ((j ^ (s&7)) << 3)) = v;
  }
  __syncthreads();
  int mt = wid;
  for (int nt = 0; nt < 4; ++nt){
    ffrag acc = {0.f, 0.f, 0.f, 0.f};
    #pragma unroll
    for (int kb = 0; kb < 16; ++kb){
      int j = kb*4 + g4;
      int rowa = mt*16 + lq, rowb = nt*16 + lq;
      bfrag af  = *(const bfrag*)(xa + rowa*512 + ((j ^ (rowa&7)) << 3));
      bfrag bf_ = *(const bfrag*)(xa + rowb*512 + ((j ^ (rowb&7)) << 3));
      acc = __builtin_amdgcn_mfma_f32_16x16x32_bf16(af, bf_, acc, 0, 0, 0);
    }
    #pragma unroll
    for (int r = 0; r < 4; ++r)
      Gb[(size_t)b*4096 + (mt*16 + g4*4 + r)*64 + nt*16 + lq] = f2bf(acc[r]);
  }
}

// -------------------- score-space fused attention --------------------
// grid (8 lg, 128 b); per phase: 32 q rows (16 Ft + 16 Pr). LDS 54.5 KB.
__global__ __launch_bounds__(256, 3) void k_attn3(const int* fl,
    const u16* __restrict__ FspAug, const u16* __restrict__ FtB, const u16* __restrict__ PrB,
    const u16* __restrict__ Gb, const float* __restrict__ invFt, const float* __restrict__ invPr,
    const void* gp_, const void* gn_, float* __restrict__ out){
  __shared__ u16 ftile[32*512];     // 32768 B
  __shared__ u16 gt[64*64];         //  8192 B
  __shared__ float aw[32*68];       //  8704 B
  __shared__ u16 a1t[32*64];        //  4096 B
  __shared__ float dts[32];         //   128 B
  __shared__ float epi[32*5];       //   640 B
  int b = blockIdx.y, lg = blockIdx.x;
  int tid = threadIdx.x, lane = tid & 63, wid = tid >> 6;
  int lq = lane & 15, g4 = lane >> 4;

  // phase-A B fragments (s-tile = wid) resident in VGPRs
  bfrag breg[16];
  {
    const u16* fa = FspAug + ((size_t)(b*64 + wid*16 + lq))*512 + g4*8;
    #pragma unroll
    for (int kb = 0; kb < 16; ++kb)
      breg[kb] = *(const bfrag*)(fa + kb*32);
  }
  // stage G (swizzled)
  for (int idx = tid; idx < 64*8; idx += 256){
    int rr = idx >> 3, j = idx & 7;
    uint4 v = *(const uint4*)(Gb + (size_t)b*4096 + rr*64 + j*8);
    *(uint4*)(gt + rr*64 + ((j ^ (rr&7)) << 3)) = v;
  }
  float fvpSq = bf2f(Gb[(size_t)b*4096 + 56*64 + 56]);
  float gp = ld_gamma(gp_, *fl), gn = ld_gamma(gn_, *fl);

  for (int t = 0; t < 8; ++t){
    int l0t = lg*128 + t*16;
    // stage ftile: rows 0-15 Ft, 16-31 Pr (pure bf16 copies)
    for (int idx = tid; idx < 32*64; idx += 256){
      int q = idx >> 6, j = idx & 63;
      const u16* src = (q < 16 ? FtB + (size_t)(l0t + q)*512
                               : PrB + (size_t)(l0t + q - 16)*512) + j*8;
      uint4 v = *(const uint4*)src;
      *(uint4*)(ftile + q*512 + ((j ^ (q&7)) << 3)) = v;
    }
    __syncthreads();   // B1
    // phase A: scores D[q, s-tile wid], K=512
    #pragma unroll
    for (int qt = 0; qt < 2; ++qt){
      ffrag acc = {0.f, 0.f, 0.f, 0.f};
      #pragma unroll
      for (int kb = 0; kb < 16; ++kb){
        int j = kb*4 + g4;
        int row = qt*16 + lq;
        bfrag af = *(const bfrag*)(ftile + row*512 + ((j ^ (row&7)) << 3));
        acc = __builtin_amdgcn_mfma_f32_16x16x32_bf16(af, breg[kb], acc, 0, 0, 0);
      }
      #pragma unroll
      for (int r = 0; r < 4; ++r)
        aw[(qt*16 + g4*4 + r)*68 + wid*16 + lq] = acc[r];
    }
    __syncthreads();   // B2
    // softmax (s<49) + dt_pv = sum(a1*raw); store a1 bf16 (swizzled rows)
    #pragma unroll
    for (int rr = 0; rr < 8; ++rr){
      int q = wid*8 + rr;
      float x = (lane < Sn) ? aw[q*68 + lane] : -1e30f;
      float mx = x;
      #pragma unroll
      for (int m = 32; m; m >>= 1) mx = fmaxf(mx, __shfl_xor(mx, m));
      float e = (lane < Sn) ? __expf(x - mx) : 0.f;
      float dx = e * x;
      float sm = e;
      #pragma unroll
      for (int m = 32; m; m >>= 1){ sm += __shfl_xor(sm, m); dx += __shfl_xor(dx, m); }
      int j = lane >> 3;
      a1t[q*64 + ((j ^ (q&7)) << 3) + (lane & 7)] = f2bf(e / sm);
      if (lane == 0) dts[q] = dx / sm;
    }
    __syncthreads();   // B3
    // gram phase: DG[q, s'-tile wid] = a1·G ; aGa partials + wv (col 56)
    #pragma unroll
    for (int qt = 0; qt < 2; ++qt){
      ffrag acc = {0.f, 0.f, 0.f, 0.f};
      #pragma unroll
      for (int kb2 = 0; kb2 < 2; ++kb2){
        int j = kb2*4 + g4;
        int row = qt*16 + lq;
        bfrag af = *(const bfrag*)(a1t + row*64 + ((j ^ (row&7)) << 3));
        int rowg = wid*16 + lq;
        bfrag bg = *(const bfrag*)(gt + rowg*64 + ((j ^ (rowg&7)) << 3));
        acc = __builtin_amdgcn_mfma_f32_16x16x32_bf16(af, bg, acc, 0, 0, 0);
      }
      int sp = wid*16 + lq;
      int j2 = sp >> 3;
      #pragma unroll
      for (int r = 0; r < 4; ++r){
        int q = qt*16 + g4*4 + r;
        float av = bf2f(a1t[q*64 + ((j2 ^ (q&7)) << 3) + (sp & 7)]);
        float p = av * acc[r];
        #pragma unroll
        for (int m = 1; m <= 8; m <<= 1) p += __shfl_xor(p, m);
        if (lq == 0) epi[q*5 + wid] = p;
        if (wid == 3 && lq == 8) epi[q*5 + 4] = acc[r];   // s' = 56 -> wv[q]
      }
    }
    __syncthreads();   // B4
    // finalize: 32 q rows -> logits
    if (tid < 32){
      int q = tid;
      int l = l0t + (q & 15);
      if (l < Ln){
        float aGa = epi[q*5+0] + epi[q*5+1] + epi[q*5+2] + epi[q*5+3];
        float wv  = epi[q*5+4];
        float gam = (q < 16) ? gp : gn;
        float ns  = gam*gam*aGa + 2.f*gam*wv + fvpSq;
        float dt  = gam*dts[q] + aw[q*68 + 56];
        float invx = (q < 16 ? invFt : invPr)[l];
        float lg2 = dt * invx / fmaxf(sqrtf(ns), 1e-12f);
        if (q < 16){
          out[(size_t)b*Ln + l]      = aw[q*68 + 57] * invx;   // logits1
          out[(size_t)BL + (size_t)b*Ln + l] = lg2;            // logits2
        } else {
          out[(size_t)2*BL + (size_t)b*Ln + l] = lg2;          // logits3
        }
      }
    }
    // no extra barrier: B1 of next phase orders ftile rewrite; aw/a1t/epi
    // rewritten only after B2'/B3' which wave0 gates by program order.
  }
}

// -------------------- prototype update (deterministic scan) -----------------
template<int BF>
__device__ void proto_body(const int* label, const float* Fvn, const void* Pr,
                           float* out, int* lab){
  int l = blockIdx.x, tid = threadIdx.x;
  if (tid < Bn) lab[tid] = label[tid];
  __syncthreads();
  float4 sum = make_float4(0.f, 0.f, 0.f, 0.f);
  int cnt = 0;
  for (int i = 0; i < Bn; ++i){
    if (lab[i] == l){
      cnt++;
      float4 v = *(const float4*)(Fvn + i*Cn + tid*4);
      sum.x += v.x; sum.y += v.y; sum.z += v.z; sum.w += v.w;
    }
  }
  int base = l*Cn + tid*4;
  float* dst = out + 3*BL + base;
  float sv[4] = {sum.x, sum.y, sum.z, sum.w};
  if (cnt > 0){
    float sc = 0.01f / fmaxf((float)cnt, 1e-8f);
    #pragma unroll
    for (int j = 0; j < 4; ++j)
      dst[j] = 0.99f*ldin<BF>(Pr, base + j) + sv[j]*sc;
  } else {
    #pragma unroll
    for (int j = 0; j < 4; ++j)
      dst[j] = ldin<BF>(Pr, base + j);
  }
}

__global__ __launch_bounds__(128) void k_proto(const int* fl, const int* label,
    const float* Fvn, const void* Pr, float* out){
  __shared__ int lab[Bn];
  if (*fl) proto_body<1>(label, Fvn, Pr, out, lab);
  else     proto_body<0>(label, Fvn, Pr, out, lab);
}

// ---------------------------------------------------------------------------
extern "C" void kernel_launch(void* const* d_in, const int* in_sizes, int n_in,
                              void* d_out, int out_size, void* d_ws, size_t ws_size,
                              hipStream_t stream){
  (void)in_sizes; (void)n_in; (void)out_size; (void)ws_size;
  const void* Fs    = d_in[0];
  const void* Ft    = d_in[1];
  const void* Fv    = d_in[2];
  const int*  label = (const int*)d_in[3];
  const void* gn1g  = d_in[4];
  const void* gn1b  = d_in[5];
  const void* c1w   = d_in[6];
  const void* c1b   = d_in[7];
  const void* gn2g  = d_in[8];
  const void* gn2b  = d_in[9];
  const void* c2w   = d_in[10];
  const void* c2b   = d_in[11];
  const void* ln1g  = d_in[12];
  const void* ln1b  = d_in[13];
  const void* l1w   = d_in[14];
  const void* l1b   = d_in[15];
  const void* ln2g  = d_in[16];
  const void* ln2b  = d_in[17];
  const void* l2w   = d_in[18];
  const void* l2b   = d_in[19];
  const void* gp    = d_in[20];
  const void* gnm   = d_in[21];
  const void* proto = d_in[22];
  float* out = (float*)d_out;
  float* ws  = (float*)d_ws;

  float* m1    = ws + 0;
  float* rs1   = ws + 128;
  float* m2    = ws + 256;
  float* rs2   = ws + 384;
  float* invFt = ws + 512;
  float* invPr = ws + 1536;
  int*   iflag = (int*)(ws + 3072);
  u16*   H1    = (u16*)(ws + 4096);                         // B*C*S bf16
  float* Fvp   = ws + 4096 + (size_t)Bn*Cn*Sn/2;            // B*C f32
  float* Fvn   = Fvp + Bn*Cn;                               // B*C f32
  u16*   FspAug= (u16*)(Fvn + Bn*Cn);                       // B*64*512 bf16
  u16*   FtB   = FspAug + (size_t)Bn*64*512;                // 1024*512 bf16
  u16*   PrB   = FtB + (size_t)1024*512;                    // 1024*512 bf16
  u16*   Gb    = PrB + (size_t)1024*512;                    // B*64*64 bf16

  k_detect<<<1, 64, 0, stream>>>(Fs, iflag);
  k_gn1_stats<<<Bn, 256, 0, stream>>>(iflag, Fs, m1, rs1);
  k_conv1<<<Bn*2, 256, 0, stream>>>(iflag, Fs, gn1g, gn1b, c1w, c1b, m1, rs1, H1);
  k_gn2_stats<<<Bn, 256, 0, stream>>>(H1, m2, rs2);
  k_conv2<<<Bn*2, 256, 0, stream>>>(iflag, H1, gn2g, gn2b, c2w, c2b, m2, rs2, FspAug);
  k_vec<<<Bn, 256, 0, stream>>>(iflag, Fv, ln1g, ln1b, l1w, l1b, ln2g, ln2b, l2w, l2b, Fvp, Fvn);
  k_prep<<<Bn, 256, 0, stream>>>(Fvp, Fvn, FspAug, Gb);
  k_protonorm<<<1024, 256, 0, stream>>>(iflag, Ft, proto, invFt, invPr, FtB, PrB);
  k_attn3<<<dim3(8, Bn), 256, 0, stream>>>(iflag, FspAug, FtB, PrB, Gb,
                                           invFt, invPr, gp, gnm, out);
  k_proto<<<Ln, 128, 0, stream>>>(iflag, label, Fvn, proto, out);
}

// Round 6
// 386.064 us; speedup vs baseline: 5.0667x; 1.3541x over previous
//
#include <hip/hip_runtime.h>

// ---------------------------------------------------------------------------
// DPM_Block — Round 6: MFMA convs (bf16 weights) + de-staged score-space attn.
// B=128, S=49, C=512, L=1000. Inputs f32 (runtime-detected), out f32.
// ws (floats): hdr 4096 | H1t bf16 [B][49][512] | Fvp | Fvn |
//   FspAug bf16 [B][64][512] | FtB/PrB bf16 [1024][512] | Gb bf16 [B][64][64]
//   | W1b/W2b bf16 [512][512]  — ~19.5 MB.
// ---------------------------------------------------------------------------

#define Bn 128
#define Sn 49
#define Cn 512
#define Ln 1000
#define BL (Bn*Ln)

typedef unsigned short u16;
typedef unsigned int u32;

using bfrag = __attribute__((ext_vector_type(8))) short;   // 8 bf16 (4 VGPR)
using ffrag = __attribute__((ext_vector_type(4))) float;   // 4 f32 acc

__device__ __forceinline__ float bf2f(u16 u){ return __uint_as_float(((u32)u) << 16); }
__device__ __forceinline__ float bflo(u32 u){ return __uint_as_float(u << 16); }
__device__ __forceinline__ float bfhi(u32 u){ return __uint_as_float(u & 0xffff0000u); }
__device__ __forceinline__ u16 f2bf(float f){
  u32 x = __float_as_uint(f);
  u32 r = x + 0x7fffu + ((x >> 16) & 1u);   // RNE
  return (u16)(r >> 16);
}

template<int BF>
__device__ __forceinline__ float ldin(const void* p, int i){
  if (BF) return bf2f(((const u16*)p)[i]);
  return ((const float*)p)[i];
}

template<int BF>
__device__ __forceinline__ void ld8(const void* p, int base, float* w){
  if (BF){
    uint4 u = *(const uint4*)((const u16*)p + base);
    w[0]=bflo(u.x); w[1]=bfhi(u.x); w[2]=bflo(u.y); w[3]=bfhi(u.y);
    w[4]=bflo(u.z); w[5]=bfhi(u.z); w[6]=bflo(u.w); w[7]=bfhi(u.w);
  } else {
    float4 a = *(const float4*)((const float*)p + base);
    float4 b = *(const float4*)((const float*)p + base + 4);
    w[0]=a.x; w[1]=a.y; w[2]=a.z; w[3]=a.w;
    w[4]=b.x; w[5]=b.y; w[6]=b.z; w[7]=b.w;
  }
}

__device__ __forceinline__ uint4 pack8(const float* w){
  uint4 v;
  v.x = (u32)f2bf(w[0]) | ((u32)f2bf(w[1])<<16);
  v.y = (u32)f2bf(w[2]) | ((u32)f2bf(w[3])<<16);
  v.z = (u32)f2bf(w[4]) | ((u32)f2bf(w[5])<<16);
  v.w = (u32)f2bf(w[6]) | ((u32)f2bf(w[7])<<16);
  return v;
}

__device__ __forceinline__ float ld_gamma(const void* p, int BF){
  float fb = bf2f(((const u16*)p)[0]);
  float ff = ((const float*)p)[0];
  bool pb = (fb > 0.05f && fb < 1.5f);
  bool pf = (ff > 0.05f && ff < 1.5f);
  if (pb && !pf) return fb;
  if (pf && !pb) return ff;
  return BF ? fb : ff;
}

// -------------------- dtype detector --------------------
__global__ void k_detect(const void* Fs, int* flag){
  int lane = threadIdx.x;
  int v = 0;
  for (int i = lane; i < 256; i += 64){
    u16 lo = ((const u16*)Fs)[2*i];
    int e = (lo >> 7) & 0xff;
    v += (e >= 0x70 && e <= 0x8f);
  }
  #pragma unroll
  for (int off = 32; off; off >>= 1) v += __shfl_xor(v, off);
  if (lane == 0) *flag = (v >= 200) ? 1 : 0;
}

__device__ __forceinline__ float2 block_red2(float a, float b, float* scratch){
  __syncthreads();
  #pragma unroll
  for (int off = 32; off; off >>= 1){ a += __shfl_xor(a, off); b += __shfl_xor(b, off); }
  int lane = threadIdx.x & 63, wid = threadIdx.x >> 6;
  if (lane == 0){ scratch[wid] = a; scratch[wid + 4] = b; }
  __syncthreads();
  return make_float2(scratch[0] + scratch[1] + scratch[2] + scratch[3],
                     scratch[4] + scratch[5] + scratch[6] + scratch[7]);
}

// -------------------- weight bf16 prep --------------------
template<int BF>
__device__ void wprep_body(const void* W1, const void* W2, u16* W1b, u16* W2b){
  int i = blockIdx.x*256 + threadIdx.x;      // 65536 threads x 8 elems
  const void* src = (i < 32768) ? W1 : W2;
  u16* dst = (i < 32768) ? W1b : W2b;
  int off = (i & 32767)*8;
  float w[8]; ld8<BF>(src, off, w);
  *(uint4*)(dst + off) = pack8(w);
}
__global__ __launch_bounds__(256) void k_wprep(const int* fl, const void* W1,
    const void* W2, u16* W1b, u16* W2b){
  if (*fl) wprep_body<1>(W1, W2, W1b, W2b); else wprep_body<0>(W1, W2, W1b, W2b);
}

// -------------------- groupnorm stats --------------------
template<int BF>
__device__ void gn1_body(const void* Fs, float* m1, float* rs1, float* red){
  int b = blockIdx.x, tid = threadIdx.x;
  float s = 0.f, ss = 0.f;
  for (int i = tid; i < Sn*Cn/8; i += 256){
    float w[8]; ld8<BF>(Fs, b*Sn*Cn + i*8, w);
    #pragma unroll
    for (int j = 0; j < 8; ++j){ s += w[j]; ss += w[j]*w[j]; }
  }
  float2 r = block_red2(s, ss, red);
  if (tid == 0){
    float m = r.x * (1.f/(Sn*Cn));
    float v = r.y * (1.f/(Sn*Cn)) - m*m;
    m1[b] = m; rs1[b] = rsqrtf(v + 1e-5f);
  }
}

__global__ __launch_bounds__(256) void k_gn1_stats(const int* fl, const void* Fs,
                                                   float* m1, float* rs1){
  __shared__ float red[8];
  if (*fl) gn1_body<1>(Fs, m1, rs1, red); else gn1_body<0>(Fs, m1, rs1, red);
}

__global__ __launch_bounds__(256) void k_gn2_stats(const u16* __restrict__ H1t,
                                                   float* __restrict__ m2, float* __restrict__ rs2){
  __shared__ float red[8];
  int b = blockIdx.x, tid = threadIdx.x;
  float s = 0.f, ss = 0.f;
  for (int i = tid; i < Sn*Cn/8; i += 256){
    float w[8]; ld8<1>(H1t, b*Sn*Cn + i*8, w);
    #pragma unroll
    for (int j = 0; j < 8; ++j){ s += w[j]; ss += w[j]*w[j]; }
  }
  float2 r = block_red2(s, ss, red);
  if (tid == 0){
    float m = r.x * (1.f/(Sn*Cn));
    float v = r.y * (1.f/(Sn*Cn)) - m*m;
    m2[b] = m; rs2[b] = rsqrtf(v + 1e-5f);
  }
}

// -------------------- MFMA conv: D[o,s] = Wb[o,c] * Xn[s,c] ----------------
// grid (2 o-halves, B). LDS: Bs [64][512] bf16 swz (64K) + An/Bc f32 (4K).
// C1=1: src=Fs (dtype BF), out=H1t bf16 [b][49][512], relu, skip s>=49.
// C1=0: src=H1t bf16, out=FspAug [b][64][512], zero rows s>=49.
template<int BF, int C1>
__device__ void convm_body(const void* src, const void* gv, const void* bv,
    const u16* __restrict__ Wb, const void* bias,
    const float* mean_, const float* rsv_, u16* dst,
    u16* Bs, float* An, float* Bc){
  int b = blockIdx.y, o0 = blockIdx.x * 256;
  int tid = threadIdx.x;
  float mean = mean_[b], rs = rsv_[b];
  for (int c = tid; c < Cn; c += 256){
    float g = ldin<BF>(gv, c), bb = ldin<BF>(bv, c);
    An[c] = rs * g; Bc[c] = bb - mean * rs * g;
  }
  __syncthreads();
  for (int idx = tid; idx < 64*64; idx += 256){
    int s = idx >> 6, j = idx & 63, c0 = j*8;
    uint4 v = {0,0,0,0};
    if (s < Sn){
      float w[8];
      if (C1) ld8<BF>(src, b*Sn*Cn + s*Cn + c0, w);
      else    ld8<1>(src, (b*Sn + s)*Cn + c0, w);
      #pragma unroll
      for (int k2 = 0; k2 < 8; ++k2) w[k2] = w[k2]*An[c0+k2] + Bc[c0+k2];
      v = pack8(w);
    }
    *(uint4*)(Bs + (s<<9) + ((j ^ (s&7))<<3)) = v;
  }
  __syncthreads();
  int lane = tid & 63, wid = tid >> 6, lq = lane & 15, g4 = lane >> 4;
  #pragma unroll
  for (int ot = 0; ot < 4; ++ot){
    int oA = o0 + wid*64 + ot*16;
    bfrag af[16];
    #pragma unroll
    for (int kb = 0; kb < 16; ++kb)
      af[kb] = *(const bfrag*)(Wb + (size_t)(oA + lq)*Cn + kb*32 + g4*8);
    ffrag acc[4];
    #pragma unroll
    for (int st = 0; st < 4; ++st) acc[st] = (ffrag){0.f,0.f,0.f,0.f};
    #pragma unroll
    for (int st = 0; st < 4; ++st){
      int srow = st*16 + lq;
      #pragma unroll
      for (int kb = 0; kb < 16; ++kb){
        bfrag bf_ = *(const bfrag*)(Bs + (srow<<9) + (((kb*4+g4) ^ (srow&7))<<3));
        acc[st] = __builtin_amdgcn_mfma_f32_16x16x32_bf16(af[kb], bf_, acc[st], 0,0,0);
      }
    }
    int ob = oA + g4*4;
    float b4[4];
    #pragma unroll
    for (int r = 0; r < 4; ++r) b4[r] = ldin<BF>(bias, ob + r);
    #pragma unroll
    for (int st = 0; st < 4; ++st){
      int s = st*16 + lq;
      u16 pk[4];
      #pragma unroll
      for (int r = 0; r < 4; ++r){
        float val = acc[st][r] + b4[r];
        if (C1) val = fmaxf(val, 0.f);
        pk[r] = f2bf(val);
      }
      if (C1){
        if (s < Sn) *(uint2*)(dst + ((size_t)(b*Sn + s)<<9) + ob) = *(const uint2*)pk;
      } else {
        if (s >= Sn){ pk[0]=0; pk[1]=0; pk[2]=0; pk[3]=0; }
        *(uint2*)(dst + ((size_t)(b*64 + s)<<9) + ob) = *(const uint2*)pk;
      }
    }
  }
}

__global__ __launch_bounds__(256, 2) void k_conv1m(const int* fl, const void* Fs,
    const void* g1, const void* bb1, const u16* W1b, const void* bias1,
    const float* m1, const float* rs1, u16* H1t){
  __shared__ u16 Bs[64*512];
  __shared__ float An[Cn], Bc[Cn];
  if (*fl) convm_body<1,1>(Fs, g1, bb1, W1b, bias1, m1, rs1, H1t, Bs, An, Bc);
  else     convm_body<0,1>(Fs, g1, bb1, W1b, bias1, m1, rs1, H1t, Bs, An, Bc);
}

__global__ __launch_bounds__(256, 2) void k_conv2m(const int* fl, const u16* H1t,
    const void* g2, const void* bb2, const u16* W2b, const void* bias2,
    const float* m2, const float* rs2, u16* FspAug){
  __shared__ u16 Bs[64*512];
  __shared__ float An[Cn], Bc[Cn];
  if (*fl) convm_body<1,0>(H1t, g2, bb2, W2b, bias2, m2, rs2, FspAug, Bs, An, Bc);
  else     convm_body<0,0>(H1t, g2, bb2, W2b, bias2, m2, rs2, FspAug, Bs, An, Bc);
}

// -------------------- vector MLP path --------------------
template<int BF>
__device__ __forceinline__ float dotrow(const void* W, int o, const float* v){
  float a0 = 0.f, a1 = 0.f;
  #pragma unroll 4
  for (int k = 0; k < Cn/8; ++k){
    float wv[8]; ld8<BF>(W, o*Cn + k*8, wv);
    const float* vv = v + k*8;
    a0 += wv[0]*vv[0] + wv[1]*vv[1] + wv[2]*vv[2] + wv[3]*vv[3];
    a1 += wv[4]*vv[4] + wv[5]*vv[5] + wv[6]*vv[6] + wv[7]*vv[7];
  }
  return a0 + a1;
}

template<int BF>
__device__ void vec_body(const void* Fv,
    const void* ln1g, const void* ln1b, const void* w1, const void* b1,
    const void* ln2g, const void* ln2b, const void* w2, const void* b2,
    float* Fvp, float* Fvn, float* va, float* red){
  int b = blockIdx.x, tid = threadIdx.x;
  float x0 = ldin<BF>(Fv, b*Cn + tid), x1 = ldin<BF>(Fv, b*Cn + tid + 256);
  float2 r = block_red2(x0 + x1, x0*x0 + x1*x1, red);
  float m = r.x * (1.f/Cn);
  float rv = rsqrtf(r.y * (1.f/Cn) - m*m + 1e-5f);
  va[tid]       = (x0 - m)*rv*ldin<BF>(ln1g, tid)       + ldin<BF>(ln1b, tid);
  va[tid + 256] = (x1 - m)*rv*ldin<BF>(ln1g, tid + 256) + ldin<BF>(ln1b, tid + 256);
  __syncthreads();
  float h0 = fmaxf(dotrow<BF>(w1, tid, va)       + ldin<BF>(b1, tid), 0.f);
  float h1 = fmaxf(dotrow<BF>(w1, tid + 256, va) + ldin<BF>(b1, tid + 256), 0.f);
  r = block_red2(h0 + h1, h0*h0 + h1*h1, red);
  m = r.x * (1.f/Cn);
  rv = rsqrtf(r.y * (1.f/Cn) - m*m + 1e-5f);
  va[tid]       = (h0 - m)*rv*ldin<BF>(ln2g, tid)       + ldin<BF>(ln2b, tid);
  va[tid + 256] = (h1 - m)*rv*ldin<BF>(ln2g, tid + 256) + ldin<BF>(ln2b, tid + 256);
  __syncthreads();
  float y0 = dotrow<BF>(w2, tid, va)       + ldin<BF>(b2, tid);
  float y1 = dotrow<BF>(w2, tid + 256, va) + ldin<BF>(b2, tid + 256);
  Fvp[b*Cn + tid] = y0; Fvp[b*Cn + tid + 256] = y1;
  r = block_red2(y0*y0 + y1*y1, 0.f, red);
  float inv = 1.f / fmaxf(sqrtf(r.x), 1e-12f);
  Fvn[b*Cn + tid] = y0*inv; Fvn[b*Cn + tid + 256] = y1*inv;
}

__global__ __launch_bounds__(256) void k_vec(const int* fl, const void* Fv,
    const void* ln1g, const void* ln1b, const void* w1, const void* b1,
    const void* ln2g, const void* ln2b, const void* w2, const void* b2,
    float* Fvp, float* Fvn){
  __shared__ float va[Cn];
  __shared__ float red[8];
  if (*fl) vec_body<1>(Fv, ln1g, ln1b, w1, b1, ln2g, ln2b, w2, b2, Fvp, Fvn, va, red);
  else     vec_body<0>(Fv, ln1g, ln1b, w1, b1, ln2g, ln2b, w2, b2, Fvp, Fvn, va, red);
}

// ------------- per-l inverse norms + bf16 copies of Ft / prototype ----------
template<int BF>
__device__ void protonorm_body(const void* Ft, const void* Pr,
                               float* invFt, float* invPr,
                               u16* FtB, u16* PrB, float* red){
  int l = blockIdx.x, tid = threadIdx.x;
  if (l >= Ln){
    FtB[(size_t)l*512 + tid] = 0; FtB[(size_t)l*512 + tid + 256] = 0;
    PrB[(size_t)l*512 + tid] = 0; PrB[(size_t)l*512 + tid + 256] = 0;
    return;
  }
  float a0 = ldin<BF>(Ft, l*Cn + tid), a1 = ldin<BF>(Ft, l*Cn + tid + 256);
  float p0 = ldin<BF>(Pr, l*Cn + tid), p1 = ldin<BF>(Pr, l*Cn + tid + 256);
  FtB[(size_t)l*512 + tid] = f2bf(a0); FtB[(size_t)l*512 + tid + 256] = f2bf(a1);
  PrB[(size_t)l*512 + tid] = f2bf(p0); PrB[(size_t)l*512 + tid + 256] = f2bf(p1);
  float2 r = block_red2(a0*a0 + a1*a1, p0*p0 + p1*p1, red);
  if (tid == 0){
    invFt[l] = 1.f / fmaxf(sqrtf(r.x), 1e-12f);
    invPr[l] = 1.f / fmaxf(sqrtf(r.y), 1e-12f);
  }
}

__global__ __launch_bounds__(256) void k_protonorm(const int* fl, const void* Ft,
    const void* Pr, float* invFt, float* invPr, u16* FtB, u16* PrB){
  __shared__ float red[8];
  if (*fl) protonorm_body<1>(Ft, Pr, invFt, invPr, FtB, PrB, red);
  else     protonorm_body<0>(Ft, Pr, invFt, invPr, FtB, PrB, red);
}

// ------------- k_prep: aug rows 56/57 <- fvp/fvn; G = Aug·Aug^T (MFMA) ------
__global__ __launch_bounds__(256) void k_prep(const float* __restrict__ Fvp,
    const float* __restrict__ Fvn, u16* __restrict__ FspAug, u16* __restrict__ Gb){
  __shared__ u16 xa[64*512];
  int b = blockIdx.x, tid = threadIdx.x;
  int lane = tid & 63, wid = tid >> 6, lq = lane & 15, g4 = lane >> 4;
  for (int idx = tid; idx < 64*64; idx += 256){
    int s = idx >> 6, j = idx & 63;
    uint4 v;
    if (s == 56 || s == 57){
      const float* src = (s == 56 ? Fvp : Fvn) + b*512 + j*8;
      float w[8];
      #pragma unroll
      for (int k = 0; k < 8; ++k) w[k] = src[k];
      v = pack8(w);
      *(uint4*)(FspAug + ((size_t)(b*64 + s))*512 + j*8) = v;
    } else {
      v = *(const uint4*)(FspAug + ((size_t)(b*64 + s))*512 + j*8);
    }
    *(uint4*)(xa + s*512 + ((j ^ (s&7)) << 3)) = v;
  }
  __syncthreads();
  int mt = wid;
  for (int nt = 0; nt < 4; ++nt){
    ffrag acc = {0.f, 0.f, 0.f, 0.f};
    #pragma unroll
    for (int kb = 0; kb < 16; ++kb){
      int j = kb*4 + g4;
      int rowa = mt*16 + lq, rowb = nt*16 + lq;
      bfrag af  = *(const bfrag*)(xa + rowa*512 + ((j ^ (rowa&7)) << 3));
      bfrag bf_ = *(const bfrag*)(xa + rowb*512 + ((j ^ (rowb&7)) << 3));
      acc = __builtin_amdgcn_mfma_f32_16x16x32_bf16(af, bf_, acc, 0, 0, 0);
    }
    #pragma unroll
    for (int r = 0; r < 4; ++r)
      Gb[(size_t)b*4096 + (mt*16 + g4*4 + r)*64 + nt*16 + lq] = f2bf(acc[r]);
  }
}

// -------------------- score-space fused attention (de-staged) ---------------
// grid (8 lg, 128 b); 4 phases x 32 l per path. LDS ~27.2 KB.
__global__ __launch_bounds__(256, 3) void k_attn3(const int* fl,
    const u16* __restrict__ FspAug, const u16* __restrict__ FtB, const u16* __restrict__ PrB,
    const u16* __restrict__ Gb, const float* __restrict__ invFt, const float* __restrict__ invPr,
    const void* gp_, const void* gn_, float* __restrict__ out){
  __shared__ float aw[64*68];     // 17408 B
  __shared__ u16 a1t[64*64];      //  8192 B
  __shared__ float dts[64];       //   256 B
  __shared__ float epi[64*5];     //  1280 B
  int b = blockIdx.y, lg = blockIdx.x;
  int tid = threadIdx.x, lane = tid & 63, wid = tid >> 6;
  int lq = lane & 15, g4 = lane >> 4;

  // B-frags: Fsp aug rows (s-tile = wid) and gram rows (G symmetric), in VGPRs
  bfrag breg[16];
  {
    const u16* fa = FspAug + ((size_t)(b*64 + wid*16 + lq))*512 + g4*8;
    #pragma unroll
    for (int kb = 0; kb < 16; ++kb) breg[kb] = *(const bfrag*)(fa + kb*32);
  }
  bfrag bg[2];
  {
    const u16* ga = Gb + (size_t)b*4096 + (wid*16 + lq)*64 + g4*8;
    bg[0] = *(const bfrag*)(ga);
    bg[1] = *(const bfrag*)(ga + 32);
  }
  float fvpSq = bf2f(Gb[(size_t)b*4096 + 56*64 + 56]);
  float gp = ld_gamma(gp_, *fl), gn = ld_gamma(gn_, *fl);

  for (int t = 0; t < 4; ++t){
    int l0t = lg*128 + t*32;
    __syncthreads();   // B0: aw free for rewrite (prev finalize done)
    // scores: q = qt*16+m ; qt 0,1 -> Ft rows l0t(+16), qt 2,3 -> Pr
    #pragma unroll
    for (int qt = 0; qt < 4; ++qt){
      const u16* base = (qt < 2) ? FtB : PrB;
      const u16* ap = base + (size_t)(l0t + ((qt & 1) << 4) + lq)*512 + g4*8;
      ffrag acc = {0.f,0.f,0.f,0.f};
      #pragma unroll
      for (int kb = 0; kb < 16; ++kb){
        bfrag af = *(const bfrag*)(ap + kb*32);
        acc = __builtin_amdgcn_mfma_f32_16x16x32_bf16(af, breg[kb], acc, 0,0,0);
      }
      #pragma unroll
      for (int r = 0; r < 4; ++r)
        aw[(qt*16 + g4*4 + r)*68 + wid*16 + lq] = acc[r];
    }
    __syncthreads();   // B2: scores ready
    // softmax over s<49; emit a1 bf16 (swizzled) + dts
    #pragma unroll
    for (int rr = 0; rr < 16; ++rr){
      int q = wid*16 + rr;
      float x = (lane < Sn) ? aw[q*68 + lane] : -1e30f;
      float mx = x;
      #pragma unroll
      for (int m = 32; m; m >>= 1) mx = fmaxf(mx, __shfl_xor(mx, m));
      float e = (lane < Sn) ? __expf(x - mx) : 0.f;
      float dx = e * x;
      float sm = e;
      #pragma unroll
      for (int m = 32; m; m >>= 1){ sm += __shfl_xor(sm, m); dx += __shfl_xor(dx, m); }
      a1t[(q<<6) + (((lane>>3) ^ (q&7))<<3) + (lane&7)] = f2bf(e / sm);
      if (lane == 0) dts[q] = dx / sm;
    }
    __syncthreads();   // B3: a1 ready
    // gram: DG[q, s'-tile wid] = a1·G ; aGa partials + wv (col 56)
    #pragma unroll
    for (int qt = 0; qt < 4; ++qt){
      int arow = qt*16 + lq;
      ffrag acc = {0.f,0.f,0.f,0.f};
      #pragma unroll
      for (int kb2 = 0; kb2 < 2; ++kb2){
        bfrag af = *(const bfrag*)(a1t + (arow<<6) + (((kb2*4+g4) ^ (arow&7))<<3));
        acc = __builtin_amdgcn_mfma_f32_16x16x32_bf16(af, bg[kb2], acc, 0,0,0);
      }
      int sp = wid*16 + lq;
      #pragma unroll
      for (int r = 0; r < 4; ++r){
        int q = qt*16 + g4*4 + r;
        float av = bf2f(a1t[(q<<6) + (((sp>>3) ^ (q&7))<<3) + (sp&7)]);
        float p = av * acc[r];
        #pragma unroll
        for (int m = 1; m <= 8; m <<= 1) p += __shfl_xor(p, m);
        if (lq == 0) epi[q*5 + wid] = p;
        if (wid == 3 && lq == 8) epi[q*5 + 4] = acc[r];   // s' = 56
      }
    }
    __syncthreads();   // B4: epi ready
    if (tid < 64){
      int q = tid;
      int l = l0t + (q & 31);
      if (l < Ln){
        float aGa = epi[q*5+0] + epi[q*5+1] + epi[q*5+2] + epi[q*5+3];
        float wv  = epi[q*5+4];
        bool isFt = q < 32;
        float gam = isFt ? gp : gn;
        float ns  = gam*gam*aGa + 2.f*gam*wv + fvpSq;
        float dt  = gam*dts[q] + aw[q*68 + 56];
        float invx = (isFt ? invFt : invPr)[l];
        float lg2 = dt * invx / fmaxf(sqrtf(ns), 1e-12f);
        if (isFt){
          out[(size_t)b*Ln + l]              = aw[q*68 + 57] * invx;  // logits1
          out[(size_t)BL + (size_t)b*Ln + l] = lg2;                    // logits2
        } else {
          out[(size_t)2*BL + (size_t)b*Ln + l] = lg2;                  // logits3
        }
      }
    }
  }
}

// -------------------- prototype update (deterministic scan) -----------------
template<int BF>
__device__ void proto_body(const int* label, const float* Fvn, const void* Pr,
                           float* out, int* lab){
  int l = blockIdx.x, tid = threadIdx.x;
  if (tid < Bn) lab[tid] = label[tid];
  __syncthreads();
  float4 sum = make_float4(0.f, 0.f, 0.f, 0.f);
  int cnt = 0;
  for (int i = 0; i < Bn; ++i){
    if (lab[i] == l){
      cnt++;
      float4 v = *(const float4*)(Fvn + i*Cn + tid*4);
      sum.x += v.x; sum.y += v.y; sum.z += v.z; sum.w += v.w;
    }
  }
  int base = l*Cn + tid*4;
  float* dst = out + 3*BL + base;
  float sv[4] = {sum.x, sum.y, sum.z, sum.w};
  if (cnt > 0){
    float sc = 0.01f / fmaxf((float)cnt, 1e-8f);
    #pragma unroll
    for (int j = 0; j < 4; ++j)
      dst[j] = 0.99f*ldin<BF>(Pr, base + j) + sv[j]*sc;
  } else {
    #pragma unroll
    for (int j = 0; j < 4; ++j)
      dst[j] = ldin<BF>(Pr, base + j);
  }
}

__global__ __launch_bounds__(128) void k_proto(const int* fl, const int* label,
    const float* Fvn, const void* Pr, float* out){
  __shared__ int lab[Bn];
  if (*fl) proto_body<1>(label, Fvn, Pr, out, lab);
  else     proto_body<0>(label, Fvn, Pr, out, lab);
}

// ---------------------------------------------------------------------------
extern "C" void kernel_launch(void* const* d_in, const int* in_sizes, int n_in,
                              void* d_out, int out_size, void* d_ws, size_t ws_size,
                              hipStream_t stream){
  (void)in_sizes; (void)n_in; (void)out_size; (void)ws_size;
  const void* Fs    = d_in[0];
  const void* Ft    = d_in[1];
  const void* Fv    = d_in[2];
  const int*  label = (const int*)d_in[3];
  const void* gn1g  = d_in[4];
  const void* gn1b  = d_in[5];
  const void* c1w   = d_in[6];
  const void* c1b   = d_in[7];
  const void* gn2g  = d_in[8];
  const void* gn2b  = d_in[9];
  const void* c2w   = d_in[10];
  const void* c2b   = d_in[11];
  const void* ln1g  = d_in[12];
  const void* ln1b  = d_in[13];
  const void* l1w   = d_in[14];
  const void* l1b   = d_in[15];
  const void* ln2g  = d_in[16];
  const void* ln2b  = d_in[17];
  const void* l2w   = d_in[18];
  const void* l2b   = d_in[19];
  const void* gp    = d_in[20];
  const void* gnm   = d_in[21];
  const void* proto = d_in[22];
  float* out = (float*)d_out;
  float* ws  = (float*)d_ws;

  float* m1    = ws + 0;
  float* rs1   = ws + 128;
  float* m2    = ws + 256;
  float* rs2   = ws + 384;
  float* invFt = ws + 512;
  float* invPr = ws + 1536;
  int*   iflag = (int*)(ws + 3072);
  u16*   H1t   = (u16*)(ws + 4096);                 // B*49*512 bf16
  float* Fvp   = ws + 4096 + (size_t)Bn*Sn*Cn/2;
  float* Fvn   = Fvp + Bn*Cn;
  u16*   FspAug= (u16*)(Fvn + Bn*Cn);               // B*64*512 bf16
  u16*   FtB   = FspAug + (size_t)Bn*64*512;        // 1024*512 bf16
  u16*   PrB   = FtB + (size_t)1024*512;
  u16*   Gb    = PrB + (size_t)1024*512;            // B*64*64 bf16
  u16*   W1b   = Gb + (size_t)Bn*4096;              // 512*512 bf16
  u16*   W2b   = W1b + (size_t)512*512;

  k_detect<<<1, 64, 0, stream>>>(Fs, iflag);
  k_gn1_stats<<<Bn, 256, 0, stream>>>(iflag, Fs, m1, rs1);
  k_wprep<<<256, 256, 0, stream>>>(iflag, c1w, c2w, W1b, W2b);
  k_conv1m<<<dim3(2, Bn), 256, 0, stream>>>(iflag, Fs, gn1g, gn1b, W1b, c1b, m1, rs1, H1t);
  k_gn2_stats<<<Bn, 256, 0, stream>>>(H1t, m2, rs2);
  k_conv2m<<<dim3(2, Bn), 256, 0, stream>>>(iflag, H1t, gn2g, gn2b, W2b, c2b, m2, rs2, FspAug);
  k_vec<<<Bn, 256, 0, stream>>>(iflag, Fv, ln1g, ln1b, l1w, l1b, ln2g, ln2b, l2w, l2b, Fvp, Fvn);
  k_prep<<<Bn, 256, 0, stream>>>(Fvp, Fvn, FspAug, Gb);
  k_protonorm<<<1024, 256, 0, stream>>>(iflag, Ft, proto, invFt, invPr, FtB, PrB);
  k_attn3<<<dim3(8, Bn), 256, 0, stream>>>(iflag, FspAug, FtB, PrB, Gb,
                                           invFt, invPr, gp, gnm, out);
  k_proto<<<Ln, 128, 0, stream>>>(iflag, label, Fvn, proto, out);
}

// Round 7
// 243.707 us; speedup vs baseline: 8.0263x; 1.5841x over previous
//
#include <hip/hip_runtime.h>

// ---------------------------------------------------------------------------
// DPM_Block — Round 7: attention split into k_scores (batched MFMA GEMM ->
// f16 scores) + k_attn4 (1-wave row-per-lane softmax + gram MFMA epilogue).
// Fallback to R6 fused k_attn3 if ws too small for the 33.5MB score buffer.
// ---------------------------------------------------------------------------

#define Bn 128
#define Sn 49
#define Cn 512
#define Ln 1000
#define BL (Bn*Ln)
#define VQ 2048

typedef unsigned short u16;
typedef unsigned int u32;

using bfrag = __attribute__((ext_vector_type(8))) short;   // 8 bf16 (4 VGPR)
using ffrag = __attribute__((ext_vector_type(4))) float;   // 4 f32 acc

__device__ __forceinline__ float bf2f(u16 u){ return __uint_as_float(((u32)u) << 16); }
__device__ __forceinline__ float bflo(u32 u){ return __uint_as_float(u << 16); }
__device__ __forceinline__ float bfhi(u32 u){ return __uint_as_float(u & 0xffff0000u); }
__device__ __forceinline__ u16 f2bf(float f){
  u32 x = __float_as_uint(f);
  u32 r = x + 0x7fffu + ((x >> 16) & 1u);   // RNE
  return (u16)(r >> 16);
}
__device__ __forceinline__ u16 f2h(float f){
  _Float16 h = (_Float16)f; return *(u16*)&h;
}
__device__ __forceinline__ float h2f(u16 u){
  _Float16 h = *(_Float16*)&u; return (float)h;
}

template<int BF>
__device__ __forceinline__ float ldin(const void* p, int i){
  if (BF) return bf2f(((const u16*)p)[i]);
  return ((const float*)p)[i];
}

template<int BF>
__device__ __forceinline__ void ld8(const void* p, int base, float* w){
  if (BF){
    uint4 u = *(const uint4*)((const u16*)p + base);
    w[0]=bflo(u.x); w[1]=bfhi(u.x); w[2]=bflo(u.y); w[3]=bfhi(u.y);
    w[4]=bflo(u.z); w[5]=bfhi(u.z); w[6]=bflo(u.w); w[7]=bfhi(u.w);
  } else {
    float4 a = *(const float4*)((const float*)p + base);
    float4 b = *(const float4*)((const float*)p + base + 4);
    w[0]=a.x; w[1]=a.y; w[2]=a.z; w[3]=a.w;
    w[4]=b.x; w[5]=b.y; w[6]=b.z; w[7]=b.w;
  }
}

__device__ __forceinline__ uint4 pack8(const float* w){
  uint4 v;
  v.x = (u32)f2bf(w[0]) | ((u32)f2bf(w[1])<<16);
  v.y = (u32)f2bf(w[2]) | ((u32)f2bf(w[3])<<16);
  v.z = (u32)f2bf(w[4]) | ((u32)f2bf(w[5])<<16);
  v.w = (u32)f2bf(w[6]) | ((u32)f2bf(w[7])<<16);
  return v;
}

__device__ __forceinline__ float ld_gamma(const void* p, int BF){
  float fb = bf2f(((const u16*)p)[0]);
  float ff = ((const float*)p)[0];
  bool pb = (fb > 0.05f && fb < 1.5f);
  bool pf = (ff > 0.05f && ff < 1.5f);
  if (pb && !pf) return fb;
  if (pf && !pb) return ff;
  return BF ? fb : ff;
}

// -------------------- dtype detector --------------------
__global__ void k_detect(const void* Fs, int* flag){
  int lane = threadIdx.x;
  int v = 0;
  for (int i = lane; i < 256; i += 64){
    u16 lo = ((const u16*)Fs)[2*i];
    int e = (lo >> 7) & 0xff;
    v += (e >= 0x70 && e <= 0x8f);
  }
  #pragma unroll
  for (int off = 32; off; off >>= 1) v += __shfl_xor(v, off);
  if (lane == 0) *flag = (v >= 200) ? 1 : 0;
}

__device__ __forceinline__ float2 block_red2(float a, float b, float* scratch){
  __syncthreads();
  #pragma unroll
  for (int off = 32; off; off >>= 1){ a += __shfl_xor(a, off); b += __shfl_xor(b, off); }
  int lane = threadIdx.x & 63, wid = threadIdx.x >> 6;
  if (lane == 0){ scratch[wid] = a; scratch[wid + 4] = b; }
  __syncthreads();
  return make_float2(scratch[0] + scratch[1] + scratch[2] + scratch[3],
                     scratch[4] + scratch[5] + scratch[6] + scratch[7]);
}

// -------------------- weight bf16 prep --------------------
template<int BF>
__device__ void wprep_body(const void* W1, const void* W2, u16* W1b, u16* W2b){
  int i = blockIdx.x*256 + threadIdx.x;
  const void* src = (i < 32768) ? W1 : W2;
  u16* dst = (i < 32768) ? W1b : W2b;
  int off = (i & 32767)*8;
  float w[8]; ld8<BF>(src, off, w);
  *(uint4*)(dst + off) = pack8(w);
}
__global__ __launch_bounds__(256) void k_wprep(const int* fl, const void* W1,
    const void* W2, u16* W1b, u16* W2b){
  if (*fl) wprep_body<1>(W1, W2, W1b, W2b); else wprep_body<0>(W1, W2, W1b, W2b);
}

// -------------------- groupnorm stats --------------------
template<int BF>
__device__ void gn1_body(const void* Fs, float* m1, float* rs1, float* red){
  int b = blockIdx.x, tid = threadIdx.x;
  float s = 0.f, ss = 0.f;
  for (int i = tid; i < Sn*Cn/8; i += 256){
    float w[8]; ld8<BF>(Fs, b*Sn*Cn + i*8, w);
    #pragma unroll
    for (int j = 0; j < 8; ++j){ s += w[j]; ss += w[j]*w[j]; }
  }
  float2 r = block_red2(s, ss, red);
  if (tid == 0){
    float m = r.x * (1.f/(Sn*Cn));
    float v = r.y * (1.f/(Sn*Cn)) - m*m;
    m1[b] = m; rs1[b] = rsqrtf(v + 1e-5f);
  }
}

__global__ __launch_bounds__(256) void k_gn1_stats(const int* fl, const void* Fs,
                                                   float* m1, float* rs1){
  __shared__ float red[8];
  if (*fl) gn1_body<1>(Fs, m1, rs1, red); else gn1_body<0>(Fs, m1, rs1, red);
}

__global__ __launch_bounds__(256) void k_gn2_stats(const u16* __restrict__ H1t,
                                                   float* __restrict__ m2, float* __restrict__ rs2){
  __shared__ float red[8];
  int b = blockIdx.x, tid = threadIdx.x;
  float s = 0.f, ss = 0.f;
  for (int i = tid; i < Sn*Cn/8; i += 256){
    float w[8]; ld8<1>(H1t, b*Sn*Cn + i*8, w);
    #pragma unroll
    for (int j = 0; j < 8; ++j){ s += w[j]; ss += w[j]*w[j]; }
  }
  float2 r = block_red2(s, ss, red);
  if (tid == 0){
    float m = r.x * (1.f/(Sn*Cn));
    float v = r.y * (1.f/(Sn*Cn)) - m*m;
    m2[b] = m; rs2[b] = rsqrtf(v + 1e-5f);
  }
}

// -------------------- MFMA conv: D[o,s] = Wb[o,c] * Xn[s,c] ----------------
template<int BF, int C1>
__device__ void convm_body(const void* src, const void* gv, const void* bv,
    const u16* __restrict__ Wb, const void* bias,
    const float* mean_, const float* rsv_, u16* dst,
    u16* Bs, float* An, float* Bc){
  int b = blockIdx.y, o0 = blockIdx.x * 256;
  int tid = threadIdx.x;
  float mean = mean_[b], rs = rsv_[b];
  for (int c = tid; c < Cn; c += 256){
    float g = ldin<BF>(gv, c), bb = ldin<BF>(bv, c);
    An[c] = rs * g; Bc[c] = bb - mean * rs * g;
  }
  __syncthreads();
  for (int idx = tid; idx < 64*64; idx += 256){
    int s = idx >> 6, j = idx & 63, c0 = j*8;
    uint4 v = {0,0,0,0};
    if (s < Sn){
      float w[8];
      if (C1) ld8<BF>(src, b*Sn*Cn + s*Cn + c0, w);
      else    ld8<1>(src, (b*Sn + s)*Cn + c0, w);
      #pragma unroll
      for (int k2 = 0; k2 < 8; ++k2) w[k2] = w[k2]*An[c0+k2] + Bc[c0+k2];
      v = pack8(w);
    }
    *(uint4*)(Bs + (s<<9) + ((j ^ (s&7))<<3)) = v;
  }
  __syncthreads();
  int lane = tid & 63, wid = tid >> 6, lq = lane & 15, g4 = lane >> 4;
  #pragma unroll
  for (int ot = 0; ot < 4; ++ot){
    int oA = o0 + wid*64 + ot*16;
    bfrag af[16];
    #pragma unroll
    for (int kb = 0; kb < 16; ++kb)
      af[kb] = *(const bfrag*)(Wb + (size_t)(oA + lq)*Cn + kb*32 + g4*8);
    ffrag acc[4];
    #pragma unroll
    for (int st = 0; st < 4; ++st) acc[st] = (ffrag){0.f,0.f,0.f,0.f};
    #pragma unroll
    for (int st = 0; st < 4; ++st){
      int srow = st*16 + lq;
      #pragma unroll
      for (int kb = 0; kb < 16; ++kb){
        bfrag bf_ = *(const bfrag*)(Bs + (srow<<9) + (((kb*4+g4) ^ (srow&7))<<3));
        acc[st] = __builtin_amdgcn_mfma_f32_16x16x32_bf16(af[kb], bf_, acc[st], 0,0,0);
      }
    }
    int ob = oA + g4*4;
    float b4[4];
    #pragma unroll
    for (int r = 0; r < 4; ++r) b4[r] = ldin<BF>(bias, ob + r);
    #pragma unroll
    for (int st = 0; st < 4; ++st){
      int s = st*16 + lq;
      u16 pk[4];
      #pragma unroll
      for (int r = 0; r < 4; ++r){
        float val = acc[st][r] + b4[r];
        if (C1) val = fmaxf(val, 0.f);
        pk[r] = f2bf(val);
      }
      if (C1){
        if (s < Sn) *(uint2*)(dst + ((size_t)(b*Sn + s)<<9) + ob) = *(const uint2*)pk;
      } else {
        if (s >= Sn){ pk[0]=0; pk[1]=0; pk[2]=0; pk[3]=0; }
        *(uint2*)(dst + ((size_t)(b*64 + s)<<9) + ob) = *(const uint2*)pk;
      }
    }
  }
}

__global__ __launch_bounds__(256, 2) void k_conv1m(const int* fl, const void* Fs,
    const void* g1, const void* bb1, const u16* W1b, const void* bias1,
    const float* m1, const float* rs1, u16* H1t){
  __shared__ u16 Bs[64*512];
  __shared__ float An[Cn], Bc[Cn];
  if (*fl) convm_body<1,1>(Fs, g1, bb1, W1b, bias1, m1, rs1, H1t, Bs, An, Bc);
  else     convm_body<0,1>(Fs, g1, bb1, W1b, bias1, m1, rs1, H1t, Bs, An, Bc);
}

__global__ __launch_bounds__(256, 2) void k_conv2m(const int* fl, const u16* H1t,
    const void* g2, const void* bb2, const u16* W2b, const void* bias2,
    const float* m2, const float* rs2, u16* FspAug){
  __shared__ u16 Bs[64*512];
  __shared__ float An[Cn], Bc[Cn];
  if (*fl) convm_body<1,0>(H1t, g2, bb2, W2b, bias2, m2, rs2, FspAug, Bs, An, Bc);
  else     convm_body<0,0>(H1t, g2, bb2, W2b, bias2, m2, rs2, FspAug, Bs, An, Bc);
}

// -------------------- vector MLP path --------------------
template<int BF>
__device__ __forceinline__ float dotrow(const void* W, int o, const float* v){
  float a0 = 0.f, a1 = 0.f;
  #pragma unroll 4
  for (int k = 0; k < Cn/8; ++k){
    float wv[8]; ld8<BF>(W, o*Cn + k*8, wv);
    const float* vv = v + k*8;
    a0 += wv[0]*vv[0] + wv[1]*vv[1] + wv[2]*vv[2] + wv[3]*vv[3];
    a1 += wv[4]*vv[4] + wv[5]*vv[5] + wv[6]*vv[6] + wv[7]*vv[7];
  }
  return a0 + a1;
}

template<int BF>
__device__ void vec_body(const void* Fv,
    const void* ln1g, const void* ln1b, const void* w1, const void* b1,
    const void* ln2g, const void* ln2b, const void* w2, const void* b2,
    float* Fvp, float* Fvn, float* va, float* red){
  int b = blockIdx.x, tid = threadIdx.x;
  float x0 = ldin<BF>(Fv, b*Cn + tid), x1 = ldin<BF>(Fv, b*Cn + tid + 256);
  float2 r = block_red2(x0 + x1, x0*x0 + x1*x1, red);
  float m = r.x * (1.f/Cn);
  float rv = rsqrtf(r.y * (1.f/Cn) - m*m + 1e-5f);
  va[tid]       = (x0 - m)*rv*ldin<BF>(ln1g, tid)       + ldin<BF>(ln1b, tid);
  va[tid + 256] = (x1 - m)*rv*ldin<BF>(ln1g, tid + 256) + ldin<BF>(ln1b, tid + 256);
  __syncthreads();
  float h0 = fmaxf(dotrow<BF>(w1, tid, va)       + ldin<BF>(b1, tid), 0.f);
  float h1 = fmaxf(dotrow<BF>(w1, tid + 256, va) + ldin<BF>(b1, tid + 256), 0.f);
  r = block_red2(h0 + h1, h0*h0 + h1*h1, red);
  m = r.x * (1.f/Cn);
  rv = rsqrtf(r.y * (1.f/Cn) - m*m + 1e-5f);
  va[tid]       = (h0 - m)*rv*ldin<BF>(ln2g, tid)       + ldin<BF>(ln2b, tid);
  va[tid + 256] = (h1 - m)*rv*ldin<BF>(ln2g, tid + 256) + ldin<BF>(ln2b, tid + 256);
  __syncthreads();
  float y0 = dotrow<BF>(w2, tid, va)       + ldin<BF>(b2, tid);
  float y1 = dotrow<BF>(w2, tid + 256, va) + ldin<BF>(b2, tid + 256);
  Fvp[b*Cn + tid] = y0; Fvp[b*Cn + tid + 256] = y1;
  r = block_red2(y0*y0 + y1*y1, 0.f, red);
  float inv = 1.f / fmaxf(sqrtf(r.x), 1e-12f);
  Fvn[b*Cn + tid] = y0*inv; Fvn[b*Cn + tid + 256] = y1*inv;
}

__global__ __launch_bounds__(256) void k_vec(const int* fl, const void* Fv,
    const void* ln1g, const void* ln1b, const void* w1, const void* b1,
    const void* ln2g, const void* ln2b, const void* w2, const void* b2,
    float* Fvp, float* Fvn){
  __shared__ float va[Cn];
  __shared__ float red[8];
  if (*fl) vec_body<1>(Fv, ln1g, ln1b, w1, b1, ln2g, ln2b, w2, b2, Fvp, Fvn, va, red);
  else     vec_body<0>(Fv, ln1g, ln1b, w1, b1, ln2g, ln2b, w2, b2, Fvp, Fvn, va, red);
}

// ------------- per-l inverse norms + bf16 copies of Ft / prototype ----------
template<int BF>
__device__ void protonorm_body(const void* Ft, const void* Pr,
                               float* invFt, float* invPr,
                               u16* FtB, u16* PrB, float* red){
  int l = blockIdx.x, tid = threadIdx.x;
  if (l >= Ln){
    FtB[(size_t)l*512 + tid] = 0; FtB[(size_t)l*512 + tid + 256] = 0;
    PrB[(size_t)l*512 + tid] = 0; PrB[(size_t)l*512 + tid + 256] = 0;
    return;
  }
  float a0 = ldin<BF>(Ft, l*Cn + tid), a1 = ldin<BF>(Ft, l*Cn + tid + 256);
  float p0 = ldin<BF>(Pr, l*Cn + tid), p1 = ldin<BF>(Pr, l*Cn + tid + 256);
  FtB[(size_t)l*512 + tid] = f2bf(a0); FtB[(size_t)l*512 + tid + 256] = f2bf(a1);
  PrB[(size_t)l*512 + tid] = f2bf(p0); PrB[(size_t)l*512 + tid + 256] = f2bf(p1);
  float2 r = block_red2(a0*a0 + a1*a1, p0*p0 + p1*p1, red);
  if (tid == 0){
    invFt[l] = 1.f / fmaxf(sqrtf(r.x), 1e-12f);
    invPr[l] = 1.f / fmaxf(sqrtf(r.y), 1e-12f);
  }
}

__global__ __launch_bounds__(256) void k_protonorm(const int* fl, const void* Ft,
    const void* Pr, float* invFt, float* invPr, u16* FtB, u16* PrB){
  __shared__ float red[8];
  if (*fl) protonorm_body<1>(Ft, Pr, invFt, invPr, FtB, PrB, red);
  else     protonorm_body<0>(Ft, Pr, invFt, invPr, FtB, PrB, red);
}

// ------------- k_prep: aug rows 56/57 <- fvp/fvn; G = Aug·Aug^T (MFMA) ------
__global__ __launch_bounds__(256) void k_prep(const float* __restrict__ Fvp,
    const float* __restrict__ Fvn, u16* __restrict__ FspAug, u16* __restrict__ Gb){
  __shared__ u16 xa[64*512];
  int b = blockIdx.x, tid = threadIdx.x;
  int lane = tid & 63, wid = tid >> 6, lq = lane & 15, g4 = lane >> 4;
  for (int idx = tid; idx < 64*64; idx += 256){
    int s = idx >> 6, j = idx & 63;
    uint4 v;
    if (s == 56 || s == 57){
      const float* src = (s == 56 ? Fvp : Fvn) + b*512 + j*8;
      float w[8];
      #pragma unroll
      for (int k = 0; k < 8; ++k) w[k] = src[k];
      v = pack8(w);
      *(uint4*)(FspAug + ((size_t)(b*64 + s))*512 + j*8) = v;
    } else {
      v = *(const uint4*)(FspAug + ((size_t)(b*64 + s))*512 + j*8);
    }
    *(uint4*)(xa + s*512 + ((j ^ (s&7)) << 3)) = v;
  }
  __syncthreads();
  int mt = wid;
  for (int nt = 0; nt < 4; ++nt){
    ffrag acc = {0.f, 0.f, 0.f, 0.f};
    #pragma unroll
    for (int kb = 0; kb < 16; ++kb){
      int j = kb*4 + g4;
      int rowa = mt*16 + lq, rowb = nt*16 + lq;
      bfrag af  = *(const bfrag*)(xa + rowa*512 + ((j ^ (rowa&7)) << 3));
      bfrag bf_ = *(const bfrag*)(xa + rowb*512 + ((j ^ (rowb&7)) << 3));
      acc = __builtin_amdgcn_mfma_f32_16x16x32_bf16(af, bf_, acc, 0, 0, 0);
    }
    #pragma unroll
    for (int r = 0; r < 4; ++r)
      Gb[(size_t)b*4096 + (mt*16 + g4*4 + r)*64 + nt*16 + lq] = f2bf(acc[r]);
  }
}

// -------------------- K1: scores GEMM -> f16 --------------------
// grid (32 qtile, B). D[l, s] = LB[l,c] · FspAug[b][s,c]. LDS: A chunk 32KB.
__global__ __launch_bounds__(256) void k_scores(const u16* __restrict__ LB,
    const u16* __restrict__ FspAug, u16* __restrict__ Sc){
  __shared__ u16 At[64*256];   // 32768 B, swizzled
  int b = blockIdx.y, qi = blockIdx.x;
  int tid = threadIdx.x, lane = tid & 63, wid = tid >> 6;
  int lq = lane & 15, g4 = lane >> 4;
  bfrag breg[16];
  {
    const u16* fa = FspAug + ((size_t)(b*64 + wid*16 + lq))*512 + g4*8;
    #pragma unroll
    for (int kb = 0; kb < 16; ++kb) breg[kb] = *(const bfrag*)(fa + kb*32);
  }
  ffrag acc[4];
  #pragma unroll
  for (int lt = 0; lt < 4; ++lt) acc[lt] = (ffrag){0.f,0.f,0.f,0.f};
  for (int kc = 0; kc < 2; ++kc){
    if (kc) __syncthreads();
    for (int idx = tid; idx < 64*32; idx += 256){
      int r = idx >> 5, cu = idx & 31;
      uint4 v = *(const uint4*)(LB + (size_t)(qi*64 + r)*512 + kc*256 + cu*8);
      *(uint4*)(At + (r<<8) + ((cu ^ (r&7))<<3)) = v;
    }
    __syncthreads();
    #pragma unroll
    for (int kb = 0; kb < 8; ++kb){
      #pragma unroll
      for (int lt = 0; lt < 4; ++lt){
        int row = lt*16 + lq;
        bfrag af = *(const bfrag*)(At + (row<<8) + (((kb*4+g4) ^ (row&7))<<3));
        acc[lt] = __builtin_amdgcn_mfma_f32_16x16x32_bf16(af, breg[kc*8+kb], acc[lt], 0,0,0);
      }
    }
  }
  #pragma unroll
  for (int lt = 0; lt < 4; ++lt){
    #pragma unroll
    for (int r = 0; r < 4; ++r){
      size_t row = (size_t)b*VQ + qi*64 + lt*16 + g4*4 + r;
      Sc[row*64 + wid*16 + lq] = f2h(acc[lt][r]);
    }
  }
}

// -------------------- K2: row-per-lane softmax + gram epilogue --------------
// grid (32 qtile, B), 64 threads (1 wave). LDS ~9.7KB, no __syncthreads.
__global__ __launch_bounds__(64) void k_attn4(const int* fl,
    const u16* __restrict__ Sc, const u16* __restrict__ Gb,
    const float* __restrict__ invFt, const float* __restrict__ invPr,
    const void* gp_, const void* gn_, float* __restrict__ out){
  __shared__ u16 a1t[64*72];    // row pitch 72 u16 (144B, 16B-aligned)
  __shared__ float agab[64], wvb[64];
  int b = blockIdx.y, qi = blockIdx.x;
  int lane = threadIdx.x;
  int lq = lane & 15, g4 = lane >> 4;

  // load this lane's score row (64 f16 = 8 uint4; L1-backed across lanes)
  u32 w32[32];
  {
    const uint4* rp = (const uint4*)(Sc + ((size_t)b*VQ + qi*64 + lane)*64);
    #pragma unroll
    for (int i = 0; i < 8; ++i){
      uint4 v = rp[i];
      w32[i*4+0] = v.x; w32[i*4+1] = v.y; w32[i*4+2] = v.z; w32[i*4+3] = v.w;
    }
  }
  #define XS(s) h2f((u16)(((s)&1) ? (w32[(s)>>1] >> 16) : (w32[(s)>>1] & 0xffffu)))
  float mx = -1e30f;
  #pragma unroll
  for (int s = 0; s < Sn; ++s) mx = fmaxf(mx, XS(s));
  float raw56 = XS(56), raw57 = XS(57);
  float sm = 0.f, dx = 0.f;
  #pragma unroll
  for (int u = 0; u < 7; ++u){
    u32 pw[4];
    #pragma unroll
    for (int i = 0; i < 4; ++i){
      u32 w2 = 0;
      #pragma unroll
      for (int h = 0; h < 2; ++h){
        int s = u*8 + i*2 + h;
        float x = XS(s);
        float e = (s < Sn) ? __expf(x - mx) : 0.f;
        sm += e; dx += e * x;
        w2 |= ((u32)f2bf(e)) << (16*h);
      }
      pw[i] = w2;
    }
    *(uint4*)(a1t + lane*72 + u*8) = make_uint4(pw[0], pw[1], pw[2], pw[3]);
  }
  #undef XS

  // gram: D2[q, s'] = sum_s ehat[q,s] G[s', s]; per qt: aGa partial + wv col 56
  const u16* gbase = Gb + (size_t)b*4096;
  #pragma unroll
  for (int qt = 0; qt < 4; ++qt){
    float pr[4] = {0.f, 0.f, 0.f, 0.f};
    float wvl[4] = {0.f, 0.f, 0.f, 0.f};
    #pragma unroll
    for (int nt = 0; nt < 4; ++nt){
      ffrag acc = {0.f, 0.f, 0.f, 0.f};
      #pragma unroll
      for (int kb2 = 0; kb2 < 2; ++kb2){
        bfrag af;
        if (kb2 == 1 && g4 == 3) af = (bfrag){0,0,0,0,0,0,0,0};
        else af = *(const bfrag*)(a1t + (qt*16 + lq)*72 + (g4 + 4*kb2)*8);
        bfrag bg = *(const bfrag*)(gbase + (nt*16 + lq)*64 + kb2*32 + g4*8);
        acc = __builtin_amdgcn_mfma_f32_16x16x32_bf16(af, bg, acc, 0, 0, 0);
      }
      int sp = nt*16 + lq;
      #pragma unroll
      for (int r = 0; r < 4; ++r){
        int q = qt*16 + g4*4 + r;
        float av = (sp < 56) ? bf2f(a1t[q*72 + sp]) : 0.f;
        pr[r] += av * acc[r];
        if (nt == 3 && lq == 8) wvl[r] = acc[r];
      }
    }
    #pragma unroll
    for (int m = 1; m <= 8; m <<= 1){
      #pragma unroll
      for (int r = 0; r < 4; ++r) pr[r] += __shfl_xor(pr[r], m);
    }
    if (lq == 0){
      #pragma unroll
      for (int r = 0; r < 4; ++r) agab[qt*16 + g4*4 + r] = pr[r];
    }
    if (lq == 8){
      #pragma unroll
      for (int r = 0; r < 4; ++r) wvb[qt*16 + g4*4 + r] = wvl[r];
    }
  }

  // finalize (lane = row)
  int vq = qi*64 + lane;
  int path = vq >> 10, l = vq & 1023;
  if (l < Ln){
    float gp = ld_gamma(gp_, *fl), gn = ld_gamma(gn_, *fl);
    float fvpSq = bf2f(gbase[56*64 + 56]);
    float inv_sm = 1.f / sm;
    float aGa = agab[lane] * inv_sm * inv_sm;
    float wv  = wvb[lane] * inv_sm;
    float gam = path ? gn : gp;
    float ns  = gam*gam*aGa + 2.f*gam*wv + fvpSq;
    float dt  = gam*(dx*inv_sm) + raw56;
    float invx = (path ? invPr : invFt)[l];
    float lg2 = dt * invx / fmaxf(sqrtf(ns), 1e-12f);
    if (path == 0){
      out[(size_t)b*Ln + l]              = raw57 * invx;   // logits1
      out[(size_t)BL + (size_t)b*Ln + l] = lg2;            // logits2
    } else {
      out[(size_t)2*BL + (size_t)b*Ln + l] = lg2;          // logits3
    }
  }
}

// -------------------- fallback fused attention (R6) --------------------
__global__ __launch_bounds__(256, 3) void k_attn3(const int* fl,
    const u16* __restrict__ FspAug, const u16* __restrict__ FtB, const u16* __restrict__ PrB,
    const u16* __restrict__ Gb, const float* __restrict__ invFt, const float* __restrict__ invPr,
    const void* gp_, const void* gn_, float* __restrict__ out){
  __shared__ float aw[64*68];
  __shared__ u16 a1t[64*64];
  __shared__ float dts[64];
  __shared__ float epi[64*5];
  int b = blockIdx.y, lg = blockIdx.x;
  int tid = threadIdx.x, lane = tid & 63, wid = tid >> 6;
  int lq = lane & 15, g4 = lane >> 4;
  bfrag breg[16];
  {
    const u16* fa = FspAug + ((size_t)(b*64 + wid*16 + lq))*512 + g4*8;
    #pragma unroll
    for (int kb = 0; kb < 16; ++kb) breg[kb] = *(const bfrag*)(fa + kb*32);
  }
  bfrag bg[2];
  {
    const u16* ga = Gb + (size_t)b*4096 + (wid*16 + lq)*64 + g4*8;
    bg[0] = *(const bfrag*)(ga);
    bg[1] = *(const bfrag*)(ga + 32);
  }
  float fvpSq = bf2f(Gb[(size_t)b*4096 + 56*64 + 56]);
  float gp = ld_gamma(gp_, *fl), gn = ld_gamma(gn_, *fl);
  for (int t = 0; t < 4; ++t){
    int l0t = lg*128 + t*32;
    __syncthreads();
    #pragma unroll
    for (int qt = 0; qt < 4; ++qt){
      const u16* base = (qt < 2) ? FtB : PrB;
      const u16* ap = base + (size_t)(l0t + ((qt & 1) << 4) + lq)*512 + g4*8;
      ffrag acc = {0.f,0.f,0.f,0.f};
      #pragma unroll
      for (int kb = 0; kb < 16; ++kb){
        bfrag af = *(const bfrag*)(ap + kb*32);
        acc = __builtin_amdgcn_mfma_f32_16x16x32_bf16(af, breg[kb], acc, 0,0,0);
      }
      #pragma unroll
      for (int r = 0; r < 4; ++r)
        aw[(qt*16 + g4*4 + r)*68 + wid*16 + lq] = acc[r];
    }
    __syncthreads();
    #pragma unroll
    for (int rr = 0; rr < 16; ++rr){
      int q = wid*16 + rr;
      float x = (lane < Sn) ? aw[q*68 + lane] : -1e30f;
      float mxx = x;
      #pragma unroll
      for (int m = 32; m; m >>= 1) mxx = fmaxf(mxx, __shfl_xor(mxx, m));
      float e = (lane < Sn) ? __expf(x - mxx) : 0.f;
      float dxx = e * x;
      float smm = e;
      #pragma unroll
      for (int m = 32; m; m >>= 1){ smm += __shfl_xor(smm, m); dxx += __shfl_xor(dxx, m); }
      a1t[(q<<6) + (((lane>>3) ^ (q&7))<<3) + (lane&7)] = f2bf(e / smm);
      if (lane == 0) dts[q] = dxx / smm;
    }
    __syncthreads();
    #pragma unroll
    for (int qt = 0; qt < 4; ++qt){
      int arow = qt*16 + lq;
      ffrag acc = {0.f,0.f,0.f,0.f};
      #pragma unroll
      for (int kb2 = 0; kb2 < 2; ++kb2){
        bfrag af = *(const bfrag*)(a1t + (arow<<6) + (((kb2*4+g4) ^ (arow&7))<<3));
        acc = __builtin_amdgcn_mfma_f32_16x16x32_bf16(af, bg[kb2], acc, 0,0,0);
      }
      int sp = wid*16 + lq;
      #pragma unroll
      for (int r = 0; r < 4; ++r){
        int q = qt*16 + g4*4 + r;
        float av = bf2f(a1t[(q<<6) + (((sp>>3) ^ (q&7))<<3) + (sp&7)]);
        float p = av * acc[r];
        #pragma unroll
        for (int m = 1; m <= 8; m <<= 1) p += __shfl_xor(p, m);
        if (lq == 0) epi[q*5 + wid] = p;
        if (wid == 3 && lq == 8) epi[q*5 + 4] = acc[r];
      }
    }
    __syncthreads();
    if (tid < 64){
      int q = tid;
      int l = l0t + (q & 31);
      if (l < Ln){
        float aGa = epi[q*5+0] + epi[q*5+1] + epi[q*5+2] + epi[q*5+3];
        float wv  = epi[q*5+4];
        bool isFt = q < 32;
        float gam = isFt ? gp : gn;
        float ns  = gam*gam*aGa + 2.f*gam*wv + fvpSq;
        float dt  = gam*dts[q] + aw[q*68 + 56];
        float invx = (isFt ? invFt : invPr)[l];
        float lg2 = dt * invx / fmaxf(sqrtf(ns), 1e-12f);
        if (isFt){
          out[(size_t)b*Ln + l]              = aw[q*68 + 57] * invx;
          out[(size_t)BL + (size_t)b*Ln + l] = lg2;
        } else {
          out[(size_t)2*BL + (size_t)b*Ln + l] = lg2;
        }
      }
    }
  }
}

// -------------------- prototype update (deterministic scan) -----------------
template<int BF>
__device__ void proto_body(const int* label, const float* Fvn, const void* Pr,
                           float* out, int* lab){
  int l = blockIdx.x, tid = threadIdx.x;
  if (tid < Bn) lab[tid] = label[tid];
  __syncthreads();
  float4 sum = make_float4(0.f, 0.f, 0.f, 0.f);
  int cnt = 0;
  for (int i = 0; i < Bn; ++i){
    if (lab[i] == l){
      cnt++;
      float4 v = *(const float4*)(Fvn + i*Cn + tid*4);
      sum.x += v.x; sum.y += v.y; sum.z += v.z; sum.w += v.w;
    }
  }
  int base = l*Cn + tid*4;
  float* dst = out + 3*BL + base;
  float sv[4] = {sum.x, sum.y, sum.z, sum.w};
  if (cnt > 0){
    float sc = 0.01f / fmaxf((float)cnt, 1e-8f);
    #pragma unroll
    for (int j = 0; j < 4; ++j)
      dst[j] = 0.99f*ldin<BF>(Pr, base + j) + sv[j]*sc;
  } else {
    #pragma unroll
    for (int j = 0; j < 4; ++j)
      dst[j] = ldin<BF>(Pr, base + j);
  }
}

__global__ __launch_bounds__(128) void k_proto(const int* fl, const int* label,
    const float* Fvn, const void* Pr, float* out){
  __shared__ int lab[Bn];
  if (*fl) proto_body<1>(label, Fvn, Pr, out, lab);
  else     proto_body<0>(label, Fvn, Pr, out, lab);
}

// ---------------------------------------------------------------------------
extern "C" void kernel_launch(void* const* d_in, const int* in_sizes, int n_in,
                              void* d_out, int out_size, void* d_ws, size_t ws_size,
                              hipStream_t stream){
  (void)in_sizes; (void)n_in; (void)out_size;
  const void* Fs    = d_in[0];
  const void* Ft    = d_in[1];
  const void* Fv    = d_in[2];
  const int*  label = (const int*)d_in[3];
  const void* gn1g  = d_in[4];
  const void* gn1b  = d_in[5];
  const void* c1w   = d_in[6];
  const void* c1b   = d_in[7];
  const void* gn2g  = d_in[8];
  const void* gn2b  = d_in[9];
  const void* c2w   = d_in[10];
  const void* c2b   = d_in[11];
  const void* ln1g  = d_in[12];
  const void* ln1b  = d_in[13];
  const void* l1w   = d_in[14];
  const void* l1b   = d_in[15];
  const void* ln2g  = d_in[16];
  const void* ln2b  = d_in[17];
  const void* l2w   = d_in[18];
  const void* l2b   = d_in[19];
  const void* gp    = d_in[20];
  const void* gnm   = d_in[21];
  const void* proto = d_in[22];
  float* out = (float*)d_out;
  float* ws  = (float*)d_ws;

  float* m1    = ws + 0;
  float* rs1   = ws + 128;
  float* m2    = ws + 256;
  float* rs2   = ws + 384;
  float* invFt = ws + 512;
  float* invPr = ws + 1536;
  int*   iflag = (int*)(ws + 3072);
  u16*   H1t   = (u16*)(ws + 4096);                 // B*49*512 bf16
  float* Fvp   = ws + 4096 + (size_t)Bn*Sn*Cn/2;
  float* Fvn   = Fvp + Bn*Cn;
  u16*   FspAug= (u16*)(Fvn + Bn*Cn);               // B*64*512 bf16
  u16*   FtB   = FspAug + (size_t)Bn*64*512;        // 1024*512 bf16
  u16*   PrB   = FtB + (size_t)1024*512;            // contiguous after FtB
  u16*   Gb    = PrB + (size_t)1024*512;            // B*64*64 bf16
  u16*   W1b   = Gb + (size_t)Bn*4096;              // 512*512 bf16
  u16*   W2b   = W1b + (size_t)512*512;
  u16*   Sc    = W2b + (size_t)512*512;             // B*2048*64 f16 (33.5MB)
  size_t need  = (size_t)((char*)(Sc + (size_t)Bn*VQ*64) - (char*)d_ws);

  k_detect<<<1, 64, 0, stream>>>(Fs, iflag);
  k_gn1_stats<<<Bn, 256, 0, stream>>>(iflag, Fs, m1, rs1);
  k_wprep<<<256, 256, 0, stream>>>(iflag, c1w, c2w, W1b, W2b);
  k_conv1m<<<dim3(2, Bn), 256, 0, stream>>>(iflag, Fs, gn1g, gn1b, W1b, c1b, m1, rs1, H1t);
  k_gn2_stats<<<Bn, 256, 0, stream>>>(H1t, m2, rs2);
  k_conv2m<<<dim3(2, Bn), 256, 0, stream>>>(iflag, H1t, gn2g, gn2b, W2b, c2b, m2, rs2, FspAug);
  k_vec<<<Bn, 256, 0, stream>>>(iflag, Fv, ln1g, ln1b, l1w, l1b, ln2g, ln2b, l2w, l2b, Fvp, Fvn);
  k_prep<<<Bn, 256, 0, stream>>>(Fvp, Fvn, FspAug, Gb);
  k_protonorm<<<1024, 256, 0, stream>>>(iflag, Ft, proto, invFt, invPr, FtB, PrB);
  if (ws_size >= need){
    k_scores<<<dim3(32, Bn), 256, 0, stream>>>(FtB, FspAug, Sc);
    k_attn4<<<dim3(32, Bn), 64, 0, stream>>>(iflag, Sc, Gb, invFt, invPr, gp, gnm, out);
  } else {
    k_attn3<<<dim3(8, Bn), 256, 0, stream>>>(iflag, FspAug, FtB, PrB, Gb,
                                             invFt, invPr, gp, gnm, out);
  }
  k_proto<<<Ln, 128, 0, stream>>>(iflag, label, Fvn, proto, out);
}

// Round 8
// 202.668 us; speedup vs baseline: 9.6516x; 1.2025x over previous
//
#include <hip/hip_runtime.h>

// ---------------------------------------------------------------------------
// DPM_Block — Round 8: MFMA vector-MLP path (k_vg1/k_vg2/k_vl2n replaces
// k_vec), conv grid 2->4 for cross-block overlap. Rest as Round 7.
// ---------------------------------------------------------------------------

#define Bn 128
#define Sn 49
#define Cn 512
#define Ln 1000
#define BL (Bn*Ln)
#define VQ 2048

typedef unsigned short u16;
typedef unsigned int u32;

using bfrag = __attribute__((ext_vector_type(8))) short;   // 8 bf16 (4 VGPR)
using ffrag = __attribute__((ext_vector_type(4))) float;   // 4 f32 acc

__device__ __forceinline__ float bf2f(u16 u){ return __uint_as_float(((u32)u) << 16); }
__device__ __forceinline__ float bflo(u32 u){ return __uint_as_float(u << 16); }
__device__ __forceinline__ float bfhi(u32 u){ return __uint_as_float(u & 0xffff0000u); }
__device__ __forceinline__ u16 f2bf(float f){
  u32 x = __float_as_uint(f);
  u32 r = x + 0x7fffu + ((x >> 16) & 1u);   // RNE
  return (u16)(r >> 16);
}
__device__ __forceinline__ u16 f2h(float f){
  _Float16 h = (_Float16)f; return *(u16*)&h;
}
__device__ __forceinline__ float h2f(u16 u){
  _Float16 h = *(_Float16*)&u; return (float)h;
}

template<int BF>
__device__ __forceinline__ float ldin(const void* p, int i){
  if (BF) return bf2f(((const u16*)p)[i]);
  return ((const float*)p)[i];
}

template<int BF>
__device__ __forceinline__ void ld8(const void* p, int base, float* w){
  if (BF){
    uint4 u = *(const uint4*)((const u16*)p + base);
    w[0]=bflo(u.x); w[1]=bfhi(u.x); w[2]=bflo(u.y); w[3]=bfhi(u.y);
    w[4]=bflo(u.z); w[5]=bfhi(u.z); w[6]=bflo(u.w); w[7]=bfhi(u.w);
  } else {
    float4 a = *(const float4*)((const float*)p + base);
    float4 b = *(const float4*)((const float*)p + base + 4);
    w[0]=a.x; w[1]=a.y; w[2]=a.z; w[3]=a.w;
    w[4]=b.x; w[5]=b.y; w[6]=b.z; w[7]=b.w;
  }
}

__device__ __forceinline__ uint4 pack8(const float* w){
  uint4 v;
  v.x = (u32)f2bf(w[0]) | ((u32)f2bf(w[1])<<16);
  v.y = (u32)f2bf(w[2]) | ((u32)f2bf(w[3])<<16);
  v.z = (u32)f2bf(w[4]) | ((u32)f2bf(w[5])<<16);
  v.w = (u32)f2bf(w[6]) | ((u32)f2bf(w[7])<<16);
  return v;
}

__device__ __forceinline__ float ld_gamma(const void* p, int BF){
  float fb = bf2f(((const u16*)p)[0]);
  float ff = ((const float*)p)[0];
  bool pb = (fb > 0.05f && fb < 1.5f);
  bool pf = (ff > 0.05f && ff < 1.5f);
  if (pb && !pf) return fb;
  if (pf && !pb) return ff;
  return BF ? fb : ff;
}

// -------------------- dtype detector --------------------
__global__ void k_detect(const void* Fs, int* flag){
  int lane = threadIdx.x;
  int v = 0;
  for (int i = lane; i < 256; i += 64){
    u16 lo = ((const u16*)Fs)[2*i];
    int e = (lo >> 7) & 0xff;
    v += (e >= 0x70 && e <= 0x8f);
  }
  #pragma unroll
  for (int off = 32; off; off >>= 1) v += __shfl_xor(v, off);
  if (lane == 0) *flag = (v >= 200) ? 1 : 0;
}

__device__ __forceinline__ float2 block_red2(float a, float b, float* scratch){
  __syncthreads();
  #pragma unroll
  for (int off = 32; off; off >>= 1){ a += __shfl_xor(a, off); b += __shfl_xor(b, off); }
  int lane = threadIdx.x & 63, wid = threadIdx.x >> 6;
  if (lane == 0){ scratch[wid] = a; scratch[wid + 4] = b; }
  __syncthreads();
  return make_float2(scratch[0] + scratch[1] + scratch[2] + scratch[3],
                     scratch[4] + scratch[5] + scratch[6] + scratch[7]);
}

// -------------------- weight bf16 prep (4 matrices) --------------------
template<int BF>
__device__ void wprep_body(const void* W1, const void* W2, const void* W3, const void* W4,
                           u16* D1, u16* D2, u16* D3, u16* D4){
  int i = blockIdx.x*256 + threadIdx.x;     // 512 blocks x 256 = 131072 threads
  int sel = i >> 15;
  const void* src = (sel==0) ? W1 : (sel==1) ? W2 : (sel==2) ? W3 : W4;
  u16* dst = (sel==0) ? D1 : (sel==1) ? D2 : (sel==2) ? D3 : D4;
  int off = (i & 32767)*8;
  float w[8]; ld8<BF>(src, off, w);
  *(uint4*)(dst + off) = pack8(w);
}
__global__ __launch_bounds__(256) void k_wprep(const int* fl, const void* W1,
    const void* W2, const void* W3, const void* W4,
    u16* D1, u16* D2, u16* D3, u16* D4){
  if (*fl) wprep_body<1>(W1, W2, W3, W4, D1, D2, D3, D4);
  else     wprep_body<0>(W1, W2, W3, W4, D1, D2, D3, D4);
}

// -------------------- groupnorm stats --------------------
template<int BF>
__device__ void gn1_body(const void* Fs, float* m1, float* rs1, float* red){
  int b = blockIdx.x, tid = threadIdx.x;
  float s = 0.f, ss = 0.f;
  for (int i = tid; i < Sn*Cn/8; i += 256){
    float w[8]; ld8<BF>(Fs, b*Sn*Cn + i*8, w);
    #pragma unroll
    for (int j = 0; j < 8; ++j){ s += w[j]; ss += w[j]*w[j]; }
  }
  float2 r = block_red2(s, ss, red);
  if (tid == 0){
    float m = r.x * (1.f/(Sn*Cn));
    float v = r.y * (1.f/(Sn*Cn)) - m*m;
    m1[b] = m; rs1[b] = rsqrtf(v + 1e-5f);
  }
}

__global__ __launch_bounds__(256) void k_gn1_stats(const int* fl, const void* Fs,
                                                   float* m1, float* rs1){
  __shared__ float red[8];
  if (*fl) gn1_body<1>(Fs, m1, rs1, red); else gn1_body<0>(Fs, m1, rs1, red);
}

__global__ __launch_bounds__(256) void k_gn2_stats(const u16* __restrict__ H1t,
                                                   float* __restrict__ m2, float* __restrict__ rs2){
  __shared__ float red[8];
  int b = blockIdx.x, tid = threadIdx.x;
  float s = 0.f, ss = 0.f;
  for (int i = tid; i < Sn*Cn/8; i += 256){
    float w[8]; ld8<1>(H1t, b*Sn*Cn + i*8, w);
    #pragma unroll
    for (int j = 0; j < 8; ++j){ s += w[j]; ss += w[j]*w[j]; }
  }
  float2 r = block_red2(s, ss, red);
  if (tid == 0){
    float m = r.x * (1.f/(Sn*Cn));
    float v = r.y * (1.f/(Sn*Cn)) - m*m;
    m2[b] = m; rs2[b] = rsqrtf(v + 1e-5f);
  }
}

// -------------------- MFMA conv: D[o,s] = Wb[o,c] * Xn[s,c] ----------------
// grid (4 o-slices of 128, B).
template<int BF, int C1>
__device__ void convm_body(const void* src, const void* gv, const void* bv,
    const u16* __restrict__ Wb, const void* bias,
    const float* mean_, const float* rsv_, u16* dst,
    u16* Bs, float* An, float* Bc){
  int b = blockIdx.y, o0 = blockIdx.x * 128;
  int tid = threadIdx.x;
  float mean = mean_[b], rs = rsv_[b];
  for (int c = tid; c < Cn; c += 256){
    float g = ldin<BF>(gv, c), bb = ldin<BF>(bv, c);
    An[c] = rs * g; Bc[c] = bb - mean * rs * g;
  }
  __syncthreads();
  for (int idx = tid; idx < 64*64; idx += 256){
    int s = idx >> 6, j = idx & 63, c0 = j*8;
    uint4 v = {0,0,0,0};
    if (s < Sn){
      float w[8];
      if (C1) ld8<BF>(src, b*Sn*Cn + s*Cn + c0, w);
      else    ld8<1>(src, (b*Sn + s)*Cn + c0, w);
      #pragma unroll
      for (int k2 = 0; k2 < 8; ++k2) w[k2] = w[k2]*An[c0+k2] + Bc[c0+k2];
      v = pack8(w);
    }
    *(uint4*)(Bs + (s<<9) + ((j ^ (s&7))<<3)) = v;
  }
  __syncthreads();
  int lane = tid & 63, wid = tid >> 6, lq = lane & 15, g4 = lane >> 4;
  #pragma unroll
  for (int ot = 0; ot < 2; ++ot){
    int oA = o0 + wid*32 + ot*16;
    bfrag af[16];
    #pragma unroll
    for (int kb = 0; kb < 16; ++kb)
      af[kb] = *(const bfrag*)(Wb + (size_t)(oA + lq)*Cn + kb*32 + g4*8);
    ffrag acc[4];
    #pragma unroll
    for (int st = 0; st < 4; ++st) acc[st] = (ffrag){0.f,0.f,0.f,0.f};
    #pragma unroll
    for (int st = 0; st < 4; ++st){
      int srow = st*16 + lq;
      #pragma unroll
      for (int kb = 0; kb < 16; ++kb){
        bfrag bf_ = *(const bfrag*)(Bs + (srow<<9) + (((kb*4+g4) ^ (srow&7))<<3));
        acc[st] = __builtin_amdgcn_mfma_f32_16x16x32_bf16(af[kb], bf_, acc[st], 0,0,0);
      }
    }
    int ob = oA + g4*4;
    float b4[4];
    #pragma unroll
    for (int r = 0; r < 4; ++r) b4[r] = ldin<BF>(bias, ob + r);
    #pragma unroll
    for (int st = 0; st < 4; ++st){
      int s = st*16 + lq;
      u16 pk[4];
      #pragma unroll
      for (int r = 0; r < 4; ++r){
        float val = acc[st][r] + b4[r];
        if (C1) val = fmaxf(val, 0.f);
        pk[r] = f2bf(val);
      }
      if (C1){
        if (s < Sn) *(uint2*)(dst + ((size_t)(b*Sn + s)<<9) + ob) = *(const uint2*)pk;
      } else {
        if (s >= Sn){ pk[0]=0; pk[1]=0; pk[2]=0; pk[3]=0; }
        *(uint2*)(dst + ((size_t)(b*64 + s)<<9) + ob) = *(const uint2*)pk;
      }
    }
  }
}

__global__ __launch_bounds__(256, 2) void k_conv1m(const int* fl, const void* Fs,
    const void* g1, const void* bb1, const u16* W1b, const void* bias1,
    const float* m1, const float* rs1, u16* H1t){
  __shared__ u16 Bs[64*512];
  __shared__ float An[Cn], Bc[Cn];
  if (*fl) convm_body<1,1>(Fs, g1, bb1, W1b, bias1, m1, rs1, H1t, Bs, An, Bc);
  else     convm_body<0,1>(Fs, g1, bb1, W1b, bias1, m1, rs1, H1t, Bs, An, Bc);
}

__global__ __launch_bounds__(256, 2) void k_conv2m(const int* fl, const u16* H1t,
    const void* g2, const void* bb2, const u16* W2b, const void* bias2,
    const float* m2, const float* rs2, u16* FspAug){
  __shared__ u16 Bs[64*512];
  __shared__ float An[Cn], Bc[Cn];
  if (*fl) convm_body<1,0>(H1t, g2, bb2, W2b, bias2, m2, rs2, FspAug, Bs, An, Bc);
  else     convm_body<0,0>(H1t, g2, bb2, W2b, bias2, m2, rs2, FspAug, Bs, An, Bc);
}

// ------------- vector MLP: MFMA GEMM with fused row-LayerNorm ---------------
// grid 32 (16 o each). M=128 b-rows. PH=1: +relu -> bf16 out; PH=2: f32 out.
template<int BF, int SBF, int PH>
__device__ void vg_body(const void* src, const void* lng, const void* lnb,
    const u16* __restrict__ Wv, const void* bias, void* outp,
    u16* Bt, u16* Ach, float* mrow, float* rrow, float* Gc, float* Bc2){
  int o0 = blockIdx.x * 16;
  int tid = threadIdx.x, lane = tid & 63, wid = tid >> 6;
  int lq = lane & 15, g4 = lane >> 4;
  // LN params
  for (int c = tid; c < Cn; c += 256){ Gc[c] = ldin<BF>(lng, c); Bc2[c] = ldin<BF>(lnb, c); }
  // per-row LN stats: 2 threads per row
  {
    int r = tid >> 1, h = tid & 1;
    float s = 0.f, ss = 0.f;
    #pragma unroll 4
    for (int k = 0; k < 32; ++k){
      float w[8]; ld8<SBF>(src, r*Cn + h*256 + k*8, w);
      #pragma unroll
      for (int j = 0; j < 8; ++j){ s += w[j]; ss += w[j]*w[j]; }
    }
    s += __shfl_xor(s, 1); ss += __shfl_xor(ss, 1);
    if (h == 0){
      float m = s * (1.f/Cn);
      mrow[r] = m; rrow[r] = rsqrtf(ss * (1.f/Cn) - m*m + 1e-5f);
    }
  }
  // stage B tile: W rows o0..o0+15, full K
  for (int idx = tid; idx < 16*64; idx += 256){
    int row = idx >> 6, j = idx & 63;
    uint4 v = *(const uint4*)(Wv + (size_t)(o0 + row)*Cn + j*8);
    *(uint4*)(Bt + (row<<9) + ((j ^ (row&7))<<3)) = v;
  }
  __syncthreads();
  ffrag acc[2];
  acc[0] = (ffrag){0.f,0.f,0.f,0.f};
  acc[1] = (ffrag){0.f,0.f,0.f,0.f};
  for (int kc = 0; kc < 4; ++kc){
    if (kc) __syncthreads();
    for (int idx = tid; idx < 128*16; idx += 256){
      int row = idx >> 4, j = idx & 15;
      int c = kc*128 + j*8;
      float w[8]; ld8<SBF>(src, row*Cn + c, w);
      float mu = mrow[row], rsd = rrow[row];
      #pragma unroll
      for (int k2 = 0; k2 < 8; ++k2) w[k2] = (w[k2]-mu)*rsd*Gc[c+k2] + Bc2[c+k2];
      *(uint4*)(Ach + (row<<7) + ((j ^ (row&15))<<3)) = pack8(w);
    }
    __syncthreads();
    #pragma unroll
    for (int mt2 = 0; mt2 < 2; ++mt2){
      int arow = (wid*2 + mt2)*16 + lq;
      #pragma unroll
      for (int kb = 0; kb < 4; ++kb){
        bfrag af = *(const bfrag*)(Ach + (arow<<7) + (((kb*4+g4) ^ (arow&15))<<3));
        bfrag bf_ = *(const bfrag*)(Bt + (lq<<9) + (((kc*16 + kb*4 + g4) ^ (lq&7))<<3));
        acc[mt2] = __builtin_amdgcn_mfma_f32_16x16x32_bf16(af, bf_, acc[mt2], 0,0,0);
      }
    }
  }
  float bval = ldin<BF>(bias, o0 + lq);
  #pragma unroll
  for (int mt2 = 0; mt2 < 2; ++mt2){
    #pragma unroll
    for (int r = 0; r < 4; ++r){
      int brow = wid*32 + mt2*16 + g4*4 + r;
      float val = acc[mt2][r] + bval;
      if (PH == 1){
        ((u16*)outp)[brow*Cn + o0 + lq] = f2bf(fmaxf(val, 0.f));
      } else {
        ((float*)outp)[brow*Cn + o0 + lq] = val;
      }
    }
  }
}

#define VG_SHARED \
  __shared__ u16 Bt[16*512]; \
  __shared__ u16 Ach[128*128]; \
  __shared__ float mrow[128], rrow[128]; \
  __shared__ float Gc[Cn], Bc2[Cn];

__global__ __launch_bounds__(256) void k_vg1(const int* fl, const void* Fv,
    const void* lng, const void* lnb, const u16* Wv, const void* bias, u16* Hb){
  VG_SHARED
  if (*fl) vg_body<1,1,1>(Fv, lng, lnb, Wv, bias, Hb, Bt, Ach, mrow, rrow, Gc, Bc2);
  else     vg_body<0,0,1>(Fv, lng, lnb, Wv, bias, Hb, Bt, Ach, mrow, rrow, Gc, Bc2);
}

__global__ __launch_bounds__(256) void k_vg2(const int* fl, const u16* Hb,
    const void* lng, const void* lnb, const u16* Wv, const void* bias, float* Y2){
  VG_SHARED
  if (*fl) vg_body<1,1,2>(Hb, lng, lnb, Wv, bias, Y2, Bt, Ach, mrow, rrow, Gc, Bc2);
  else     vg_body<0,1,2>(Hb, lng, lnb, Wv, bias, Y2, Bt, Ach, mrow, rrow, Gc, Bc2);
}

// l2norm rows of Y2 -> Fvn (f32)
__global__ __launch_bounds__(64) void k_vl2n(const float* __restrict__ Y2,
                                             float* __restrict__ Fvn){
  int b = blockIdx.x, lane = threadIdx.x;
  const float* rp = Y2 + b*Cn + lane*8;
  float w[8];
  #pragma unroll
  for (int j = 0; j < 8; ++j) w[j] = rp[j];
  float ss = 0.f;
  #pragma unroll
  for (int j = 0; j < 8; ++j) ss += w[j]*w[j];
  #pragma unroll
  for (int m = 32; m; m >>= 1) ss += __shfl_xor(ss, m);
  float inv = 1.f / fmaxf(sqrtf(ss), 1e-12f);
  float* dp = Fvn + b*Cn + lane*8;
  #pragma unroll
  for (int j = 0; j < 8; ++j) dp[j] = w[j]*inv;
}

// ------------- per-l inverse norms + bf16 copies of Ft / prototype ----------
template<int BF>
__device__ void protonorm_body(const void* Ft, const void* Pr,
                               float* invFt, float* invPr,
                               u16* FtB, u16* PrB, float* red){
  int l = blockIdx.x, tid = threadIdx.x;
  if (l >= Ln){
    FtB[(size_t)l*512 + tid] = 0; FtB[(size_t)l*512 + tid + 256] = 0;
    PrB[(size_t)l*512 + tid] = 0; PrB[(size_t)l*512 + tid + 256] = 0;
    return;
  }
  float a0 = ldin<BF>(Ft, l*Cn + tid), a1 = ldin<BF>(Ft, l*Cn + tid + 256);
  float p0 = ldin<BF>(Pr, l*Cn + tid), p1 = ldin<BF>(Pr, l*Cn + tid + 256);
  FtB[(size_t)l*512 + tid] = f2bf(a0); FtB[(size_t)l*512 + tid + 256] = f2bf(a1);
  PrB[(size_t)l*512 + tid] = f2bf(p0); PrB[(size_t)l*512 + tid + 256] = f2bf(p1);
  float2 r = block_red2(a0*a0 + a1*a1, p0*p0 + p1*p1, red);
  if (tid == 0){
    invFt[l] = 1.f / fmaxf(sqrtf(r.x), 1e-12f);
    invPr[l] = 1.f / fmaxf(sqrtf(r.y), 1e-12f);
  }
}

__global__ __launch_bounds__(256) void k_protonorm(const int* fl, const void* Ft,
    const void* Pr, float* invFt, float* invPr, u16* FtB, u16* PrB){
  __shared__ float red[8];
  if (*fl) protonorm_body<1>(Ft, Pr, invFt, invPr, FtB, PrB, red);
  else     protonorm_body<0>(Ft, Pr, invFt, invPr, FtB, PrB, red);
}

// ------------- k_prep: aug rows 56/57 <- fvp/fvn; G = Aug·Aug^T (MFMA) ------
__global__ __launch_bounds__(256) void k_prep(const float* __restrict__ Fvp,
    const float* __restrict__ Fvn, u16* __restrict__ FspAug, u16* __restrict__ Gb){
  __shared__ u16 xa[64*512];
  int b = blockIdx.x, tid = threadIdx.x;
  int lane = tid & 63, wid = tid >> 6, lq = lane & 15, g4 = lane >> 4;
  for (int idx = tid; idx < 64*64; idx += 256){
    int s = idx >> 6, j = idx & 63;
    uint4 v;
    if (s == 56 || s == 57){
      const float* src = (s == 56 ? Fvp : Fvn) + b*512 + j*8;
      float w[8];
      #pragma unroll
      for (int k = 0; k < 8; ++k) w[k] = src[k];
      v = pack8(w);
      *(uint4*)(FspAug + ((size_t)(b*64 + s))*512 + j*8) = v;
    } else {
      v = *(const uint4*)(FspAug + ((size_t)(b*64 + s))*512 + j*8);
    }
    *(uint4*)(xa + s*512 + ((j ^ (s&7)) << 3)) = v;
  }
  __syncthreads();
  int mt = wid;
  for (int nt = 0; nt < 4; ++nt){
    ffrag acc = {0.f, 0.f, 0.f, 0.f};
    #pragma unroll
    for (int kb = 0; kb < 16; ++kb){
      int j = kb*4 + g4;
      int rowa = mt*16 + lq, rowb = nt*16 + lq;
      bfrag af  = *(const bfrag*)(xa + rowa*512 + ((j ^ (rowa&7)) << 3));
      bfrag bf_ = *(const bfrag*)(xa + rowb*512 + ((j ^ (rowb&7)) << 3));
      acc = __builtin_amdgcn_mfma_f32_16x16x32_bf16(af, bf_, acc, 0, 0, 0);
    }
    #pragma unroll
    for (int r = 0; r < 4; ++r)
      Gb[(size_t)b*4096 + (mt*16 + g4*4 + r)*64 + nt*16 + lq] = f2bf(acc[r]);
  }
}

// -------------------- K1: scores GEMM -> f16 --------------------
__global__ __launch_bounds__(256) void k_scores(const u16* __restrict__ LB,
    const u16* __restrict__ FspAug, u16* __restrict__ Sc){
  __shared__ u16 At[64*256];
  int b = blockIdx.y, qi = blockIdx.x;
  int tid = threadIdx.x, lane = tid & 63, wid = tid >> 6;
  int lq = lane & 15, g4 = lane >> 4;
  bfrag breg[16];
  {
    const u16* fa = FspAug + ((size_t)(b*64 + wid*16 + lq))*512 + g4*8;
    #pragma unroll
    for (int kb = 0; kb < 16; ++kb) breg[kb] = *(const bfrag*)(fa + kb*32);
  }
  ffrag acc[4];
  #pragma unroll
  for (int lt = 0; lt < 4; ++lt) acc[lt] = (ffrag){0.f,0.f,0.f,0.f};
  for (int kc = 0; kc < 2; ++kc){
    if (kc) __syncthreads();
    for (int idx = tid; idx < 64*32; idx += 256){
      int r = idx >> 5, cu = idx & 31;
      uint4 v = *(const uint4*)(LB + (size_t)(qi*64 + r)*512 + kc*256 + cu*8);
      *(uint4*)(At + (r<<8) + ((cu ^ (r&7))<<3)) = v;
    }
    __syncthreads();
    #pragma unroll
    for (int kb = 0; kb < 8; ++kb){
      #pragma unroll
      for (int lt = 0; lt < 4; ++lt){
        int row = lt*16 + lq;
        bfrag af = *(const bfrag*)(At + (row<<8) + (((kb*4+g4) ^ (row&7))<<3));
        acc[lt] = __builtin_amdgcn_mfma_f32_16x16x32_bf16(af, breg[kc*8+kb], acc[lt], 0,0,0);
      }
    }
  }
  #pragma unroll
  for (int lt = 0; lt < 4; ++lt){
    #pragma unroll
    for (int r = 0; r < 4; ++r){
      size_t row = (size_t)b*VQ + qi*64 + lt*16 + g4*4 + r;
      Sc[row*64 + wid*16 + lq] = f2h(acc[lt][r]);
    }
  }
}

// -------------------- K2: row-per-lane softmax + gram epilogue --------------
__global__ __launch_bounds__(64) void k_attn4(const int* fl,
    const u16* __restrict__ Sc, const u16* __restrict__ Gb,
    const float* __restrict__ invFt, const float* __restrict__ invPr,
    const void* gp_, const void* gn_, float* __restrict__ out){
  __shared__ u16 a1t[64*72];
  __shared__ float agab[64], wvb[64];
  int b = blockIdx.y, qi = blockIdx.x;
  int lane = threadIdx.x;
  int lq = lane & 15, g4 = lane >> 4;

  u32 w32[32];
  {
    const uint4* rp = (const uint4*)(Sc + ((size_t)b*VQ + qi*64 + lane)*64);
    #pragma unroll
    for (int i = 0; i < 8; ++i){
      uint4 v = rp[i];
      w32[i*4+0] = v.x; w32[i*4+1] = v.y; w32[i*4+2] = v.z; w32[i*4+3] = v.w;
    }
  }
  #define XS(s) h2f((u16)(((s)&1) ? (w32[(s)>>1] >> 16) : (w32[(s)>>1] & 0xffffu)))
  float mx = -1e30f;
  #pragma unroll
  for (int s = 0; s < Sn; ++s) mx = fmaxf(mx, XS(s));
  float raw56 = XS(56), raw57 = XS(57);
  float sm = 0.f, dx = 0.f;
  #pragma unroll
  for (int u = 0; u < 7; ++u){
    u32 pw[4];
    #pragma unroll
    for (int i = 0; i < 4; ++i){
      u32 w2 = 0;
      #pragma unroll
      for (int h = 0; h < 2; ++h){
        int s = u*8 + i*2 + h;
        float x = XS(s);
        float e = (s < Sn) ? __expf(x - mx) : 0.f;
        sm += e; dx += e * x;
        w2 |= ((u32)f2bf(e)) << (16*h);
      }
      pw[i] = w2;
    }
    *(uint4*)(a1t + lane*72 + u*8) = make_uint4(pw[0], pw[1], pw[2], pw[3]);
  }
  #undef XS

  const u16* gbase = Gb + (size_t)b*4096;
  #pragma unroll
  for (int qt = 0; qt < 4; ++qt){
    float pr[4] = {0.f, 0.f, 0.f, 0.f};
    float wvl[4] = {0.f, 0.f, 0.f, 0.f};
    #pragma unroll
    for (int nt = 0; nt < 4; ++nt){
      ffrag acc = {0.f, 0.f, 0.f, 0.f};
      #pragma unroll
      for (int kb2 = 0; kb2 < 2; ++kb2){
        bfrag af;
        if (kb2 == 1 && g4 == 3) af = (bfrag){0,0,0,0,0,0,0,0};
        else af = *(const bfrag*)(a1t + (qt*16 + lq)*72 + (g4 + 4*kb2)*8);
        bfrag bg = *(const bfrag*)(gbase + (nt*16 + lq)*64 + kb2*32 + g4*8);
        acc = __builtin_amdgcn_mfma_f32_16x16x32_bf16(af, bg, acc, 0, 0, 0);
      }
      int sp = nt*16 + lq;
      #pragma unroll
      for (int r = 0; r < 4; ++r){
        int q = qt*16 + g4*4 + r;
        float av = (sp < 56) ? bf2f(a1t[q*72 + sp]) : 0.f;
        pr[r] += av * acc[r];
        if (nt == 3 && lq == 8) wvl[r] = acc[r];
      }
    }
    #pragma unroll
    for (int m = 1; m <= 8; m <<= 1){
      #pragma unroll
      for (int r = 0; r < 4; ++r) pr[r] += __shfl_xor(pr[r], m);
    }
    if (lq == 0){
      #pragma unroll
      for (int r = 0; r < 4; ++r) agab[qt*16 + g4*4 + r] = pr[r];
    }
    if (lq == 8){
      #pragma unroll
      for (int r = 0; r < 4; ++r) wvb[qt*16 + g4*4 + r] = wvl[r];
    }
  }

  int vq = qi*64 + lane;
  int path = vq >> 10, l = vq & 1023;
  if (l < Ln){
    float gp = ld_gamma(gp_, *fl), gn = ld_gamma(gn_, *fl);
    float fvpSq = bf2f(gbase[56*64 + 56]);
    float inv_sm = 1.f / sm;
    float aGa = agab[lane] * inv_sm * inv_sm;
    float wv  = wvb[lane] * inv_sm;
    float gam = path ? gn : gp;
    float ns  = gam*gam*aGa + 2.f*gam*wv + fvpSq;
    float dt  = gam*(dx*inv_sm) + raw56;
    float invx = (path ? invPr : invFt)[l];
    float lg2 = dt * invx / fmaxf(sqrtf(ns), 1e-12f);
    if (path == 0){
      out[(size_t)b*Ln + l]              = raw57 * invx;
      out[(size_t)BL + (size_t)b*Ln + l] = lg2;
    } else {
      out[(size_t)2*BL + (size_t)b*Ln + l] = lg2;
    }
  }
}

// -------------------- fallback fused attention (R6) --------------------
__global__ __launch_bounds__(256, 3) void k_attn3(const int* fl,
    const u16* __restrict__ FspAug, const u16* __restrict__ FtB, const u16* __restrict__ PrB,
    const u16* __restrict__ Gb, const float* __restrict__ invFt, const float* __restrict__ invPr,
    const void* gp_, const void* gn_, float* __restrict__ out){
  __shared__ float aw[64*68];
  __shared__ u16 a1t[64*64];
  __shared__ float dts[64];
  __shared__ float epi[64*5];
  int b = blockIdx.y, lg = blockIdx.x;
  int tid = threadIdx.x, lane = tid & 63, wid = tid >> 6;
  int lq = lane & 15, g4 = lane >> 4;
  bfrag breg[16];
  {
    const u16* fa = FspAug + ((size_t)(b*64 + wid*16 + lq))*512 + g4*8;
    #pragma unroll
    for (int kb = 0; kb < 16; ++kb) breg[kb] = *(const bfrag*)(fa + kb*32);
  }
  bfrag bg[2];
  {
    const u16* ga = Gb + (size_t)b*4096 + (wid*16 + lq)*64 + g4*8;
    bg[0] = *(const bfrag*)(ga);
    bg[1] = *(const bfrag*)(ga + 32);
  }
  float fvpSq = bf2f(Gb[(size_t)b*4096 + 56*64 + 56]);
  float gp = ld_gamma(gp_, *fl), gn = ld_gamma(gn_, *fl);
  for (int t = 0; t < 4; ++t){
    int l0t = lg*128 + t*32;
    __syncthreads();
    #pragma unroll
    for (int qt = 0; qt < 4; ++qt){
      const u16* base = (qt < 2) ? FtB : PrB;
      const u16* ap = base + (size_t)(l0t + ((qt & 1) << 4) + lq)*512 + g4*8;
      ffrag acc = {0.f,0.f,0.f,0.f};
      #pragma unroll
      for (int kb = 0; kb < 16; ++kb){
        bfrag af = *(const bfrag*)(ap + kb*32);
        acc = __builtin_amdgcn_mfma_f32_16x16x32_bf16(af, breg[kb], acc, 0,0,0);
      }
      #pragma unroll
      for (int r = 0; r < 4; ++r)
        aw[(qt*16 + g4*4 + r)*68 + wid*16 + lq] = acc[r];
    }
    __syncthreads();
    #pragma unroll
    for (int rr = 0; rr < 16; ++rr){
      int q = wid*16 + rr;
      float x = (lane < Sn) ? aw[q*68 + lane] : -1e30f;
      float mxx = x;
      #pragma unroll
      for (int m = 32; m; m >>= 1) mxx = fmaxf(mxx, __shfl_xor(mxx, m));
      float e = (lane < Sn) ? __expf(x - mxx) : 0.f;
      float dxx = e * x;
      float smm = e;
      #pragma unroll
      for (int m = 32; m; m >>= 1){ smm += __shfl_xor(smm, m); dxx += __shfl_xor(dxx, m); }
      a1t[(q<<6) + (((lane>>3) ^ (q&7))<<3) + (lane&7)] = f2bf(e / smm);
      if (lane == 0) dts[q] = dxx / smm;
    }
    __syncthreads();
    #pragma unroll
    for (int qt = 0; qt < 4; ++qt){
      int arow = qt*16 + lq;
      ffrag acc = {0.f,0.f,0.f,0.f};
      #pragma unroll
      for (int kb2 = 0; kb2 < 2; ++kb2){
        bfrag af = *(const bfrag*)(a1t + (arow<<6) + (((kb2*4+g4) ^ (arow&7))<<3));
        acc = __builtin_amdgcn_mfma_f32_16x16x32_bf16(af, bg[kb2], acc, 0,0,0);
      }
      int sp = wid*16 + lq;
      #pragma unroll
      for (int r = 0; r < 4; ++r){
        int q = qt*16 + g4*4 + r;
        float av = bf2f(a1t[(q<<6) + (((sp>>3) ^ (q&7))<<3) + (sp&7)]);
        float p = av * acc[r];
        #pragma unroll
        for (int m = 1; m <= 8; m <<= 1) p += __shfl_xor(p, m);
        if (lq == 0) epi[q*5 + wid] = p;
        if (wid == 3 && lq == 8) epi[q*5 + 4] = acc[r];
      }
    }
    __syncthreads();
    if (tid < 64){
      int q = tid;
      int l = l0t + (q & 31);
      if (l < Ln){
        float aGa = epi[q*5+0] + epi[q*5+1] + epi[q*5+2] + epi[q*5+3];
        float wv  = epi[q*5+4];
        bool isFt = q < 32;
        float gam = isFt ? gp : gn;
        float ns  = gam*gam*aGa + 2.f*gam*wv + fvpSq;
        float dt  = gam*dts[q] + aw[q*68 + 56];
        float invx = (isFt ? invFt : invPr)[l];
        float lg2 = dt * invx / fmaxf(sqrtf(ns), 1e-12f);
        if (isFt){
          out[(size_t)b*Ln + l]              = aw[q*68 + 57] * invx;
          out[(size_t)BL + (size_t)b*Ln + l] = lg2;
        } else {
          out[(size_t)2*BL + (size_t)b*Ln + l] = lg2;
        }
      }
    }
  }
}

// -------------------- prototype update (deterministic scan) -----------------
template<int BF>
__device__ void proto_body(const int* label, const float* Fvn, const void* Pr,
                           float* out, int* lab){
  int l = blockIdx.x, tid = threadIdx.x;
  if (tid < Bn) lab[tid] = label[tid];
  __syncthreads();
  float4 sum = make_float4(0.f, 0.f, 0.f, 0.f);
  int cnt = 0;
  for (int i = 0; i < Bn; ++i){
    if (lab[i] == l){
      cnt++;
      float4 v = *(const float4*)(Fvn + i*Cn + tid*4);
      sum.x += v.x; sum.y += v.y; sum.z += v.z; sum.w += v.w;
    }
  }
  int base = l*Cn + tid*4;
  float* dst = out + 3*BL + base;
  float sv[4] = {sum.x, sum.y, sum.z, sum.w};
  if (cnt > 0){
    float sc = 0.01f / fmaxf((float)cnt, 1e-8f);
    #pragma unroll
    for (int j = 0; j < 4; ++j)
      dst[j] = 0.99f*ldin<BF>(Pr, base + j) + sv[j]*sc;
  } else {
    #pragma unroll
    for (int j = 0; j < 4; ++j)
      dst[j] = ldin<BF>(Pr, base + j);
  }
}

__global__ __launch_bounds__(128) void k_proto(const int* fl, const int* label,
    const float* Fvn, const void* Pr, float* out){
  __shared__ int lab[Bn];
  if (*fl) proto_body<1>(label, Fvn, Pr, out, lab);
  else     proto_body<0>(label, Fvn, Pr, out, lab);
}

// ---------------------------------------------------------------------------
extern "C" void kernel_launch(void* const* d_in, const int* in_sizes, int n_in,
                              void* d_out, int out_size, void* d_ws, size_t ws_size,
                              hipStream_t stream){
  (void)in_sizes; (void)n_in; (void)out_size;
  const void* Fs    = d_in[0];
  const void* Ft    = d_in[1];
  const void* Fv    = d_in[2];
  const int*  label = (const int*)d_in[3];
  const void* gn1g  = d_in[4];
  const void* gn1b  = d_in[5];
  const void* c1w   = d_in[6];
  const void* c1b   = d_in[7];
  const void* gn2g  = d_in[8];
  const void* gn2b  = d_in[9];
  const void* c2w   = d_in[10];
  const void* c2b   = d_in[11];
  const void* ln1g  = d_in[12];
  const void* ln1b  = d_in[13];
  const void* l1w   = d_in[14];
  const void* l1b   = d_in[15];
  const void* ln2g  = d_in[16];
  const void* ln2b  = d_in[17];
  const void* l2w   = d_in[18];
  const void* l2b   = d_in[19];
  const void* gp    = d_in[20];
  const void* gnm   = d_in[21];
  const void* proto = d_in[22];
  float* out = (float*)d_out;
  float* ws  = (float*)d_ws;

  float* m1    = ws + 0;
  float* rs1   = ws + 128;
  float* m2    = ws + 256;
  float* rs2   = ws + 384;
  float* invFt = ws + 512;
  float* invPr = ws + 1536;
  int*   iflag = (int*)(ws + 3072);
  u16*   H1t   = (u16*)(ws + 4096);                 // B*49*512 bf16
  float* Fvp   = ws + 4096 + (size_t)Bn*Sn*Cn/2;    // B*C f32 (= Y2)
  float* Fvn   = Fvp + Bn*Cn;
  u16*   FspAug= (u16*)(Fvn + Bn*Cn);               // B*64*512 bf16
  u16*   FtB   = FspAug + (size_t)Bn*64*512;        // 1024*512 bf16
  u16*   PrB   = FtB + (size_t)1024*512;
  u16*   Gb    = PrB + (size_t)1024*512;            // B*64*64 bf16
  u16*   W1b   = Gb + (size_t)Bn*4096;              // 512*512 bf16 x4
  u16*   W2b   = W1b + (size_t)512*512;
  u16*   W1vb  = W2b + (size_t)512*512;
  u16*   W2vb  = W1vb + (size_t)512*512;
  u16*   Hb    = W2vb + (size_t)512*512;            // 128*512 bf16
  u16*   Sc    = Hb + (size_t)Bn*Cn;                // B*2048*64 f16 (33.5MB)
  size_t need  = (size_t)((char*)(Sc + (size_t)Bn*VQ*64) - (char*)d_ws);

  k_detect<<<1, 64, 0, stream>>>(Fs, iflag);
  k_gn1_stats<<<Bn, 256, 0, stream>>>(iflag, Fs, m1, rs1);
  k_wprep<<<512, 256, 0, stream>>>(iflag, c1w, c2w, l1w, l2w, W1b, W2b, W1vb, W2vb);
  k_conv1m<<<dim3(4, Bn), 256, 0, stream>>>(iflag, Fs, gn1g, gn1b, W1b, c1b, m1, rs1, H1t);
  k_gn2_stats<<<Bn, 256, 0, stream>>>(H1t, m2, rs2);
  k_conv2m<<<dim3(4, Bn), 256, 0, stream>>>(iflag, H1t, gn2g, gn2b, W2b, c2b, m2, rs2, FspAug);
  k_vg1<<<32, 256, 0, stream>>>(iflag, Fv, ln1g, ln1b, W1vb, l1b, Hb);
  k_vg2<<<32, 256, 0, stream>>>(iflag, Hb, ln2g, ln2b, W2vb, l2b, Fvp);
  k_vl2n<<<Bn, 64, 0, stream>>>(Fvp, Fvn);
  k_prep<<<Bn, 256, 0, stream>>>(Fvp, Fvn, FspAug, Gb);
  k_protonorm<<<1024, 256, 0, stream>>>(iflag, Ft, proto, invFt, invPr, FtB, PrB);
  if (ws_size >= need){
    k_scores<<<dim3(32, Bn), 256, 0, stream>>>(FtB, FspAug, Sc);
    k_attn4<<<dim3(32, Bn), 64, 0, stream>>>(iflag, Sc, Gb, invFt, invPr, gp, gnm, out);
  } else {
    k_attn3<<<dim3(8, Bn), 256, 0, stream>>>(iflag, FspAug, FtB, PrB, Gb,
                                             invFt, invPr, gp, gnm, out);
  }
  k_proto<<<Ln, 128, 0, stream>>>(iflag, label, Fvn, proto, out);
}